// Round 2
// baseline (2370.604 us; speedup 1.0000x reference)
//
#include <hip/hip_runtime.h>
#include <math.h>

#define HID 128
#define NCLS 349
#define BN_EPS 1e-5f

__device__ __forceinline__ float lrelu(float v){ return v >= 0.f ? v : 0.01f*v; }

__global__ __launch_bounds__(256)
void k_edge_deg(const int* __restrict__ ei, const int* __restrict__ et,
                const float* __restrict__ rw0, const float* __restrict__ rw1,
                float* __restrict__ deg0, float* __restrict__ deg1, int E)
{
    int e = blockIdx.x * 256 + threadIdx.x;
    if (e >= E) return;
    int col = ei[E + e];
    int t = et[e];
    atomicAdd(deg0 + col, lrelu(rw0[t] * 100.f));
    atomicAdd(deg1 + col, lrelu(rw1[t] * 100.f));
}

__global__ __launch_bounds__(256)
void k_compact(const int* __restrict__ node_type, int* __restrict__ cnt,
               int* __restrict__ lists, int M)
{
    int i = blockIdx.x * 256 + threadIdx.x;
    if (i >= M) return;
    int t = node_type[i] & 1;
    int p = atomicAdd(cnt + t, 1);
    lists[t * M + p] = i;
}

// gathered GEMM: out[list[g]] = Xsrc[lni[list[g]]] @ W + b   (K = N = 128)
__global__ __launch_bounds__(256)
void k_gemm_group(const float* __restrict__ Xsrc, const float* __restrict__ W,
                  const float* __restrict__ bias, const int* __restrict__ list,
                  const int* __restrict__ lni, const int* __restrict__ cntp,
                  float* __restrict__ out)
{
    __shared__ float tile[64 * HID];
    __shared__ int outrow[64];
    __shared__ int srcrow[64];
    int cnt = *cntp;
    int base = blockIdx.x * 64;
    if (base >= cnt) return;
    int t = threadIdx.x;
    if (t < 64) {
        int g = base + t;
        int node = (g < cnt) ? list[g] : -1;
        outrow[t] = node;
        srcrow[t] = (node >= 0) ? lni[node] : 0;
    }
    __syncthreads();
    for (int flat = t; flat < 64 * HID; flat += 256) {
        int r = flat >> 7;
        int c = flat & 127;
        tile[flat] = (outrow[r] >= 0) ? Xsrc[(size_t)srcrow[r] * HID + c] : 0.f;
    }
    __syncthreads();
    int nl = t & 31, mg = t >> 5;
    float acc[8][4];
#pragma unroll
    for (int m = 0; m < 8; m++)
#pragma unroll
        for (int c = 0; c < 4; c++) acc[m][c] = 0.f;
    for (int k = 0; k < HID; k++) {
        float w[4];
#pragma unroll
        for (int c = 0; c < 4; c++) w[c] = W[k * HID + nl + 32 * c];
#pragma unroll
        for (int m = 0; m < 8; m++) {
            float xm = tile[(mg * 8 + m) * HID + k];
#pragma unroll
            for (int c = 0; c < 4; c++) acc[m][c] += xm * w[c];
        }
    }
#pragma unroll
    for (int m = 0; m < 8; m++) {
        int r = mg * 8 + m;
        int node = outrow[r];
        if (node < 0) continue;
#pragma unroll
        for (int c = 0; c < 4; c++) {
            int n = nl + 32 * c;
            out[(size_t)node * HID + n] = acc[m][c] + bias[n];
        }
    }
}

// agg[col] += (w_rel / |deg[col]|) * src[row]   -- one wave per edge, 2 ch/lane
__global__ __launch_bounds__(256)
void k_scatter(const float* __restrict__ src, const int* __restrict__ ei,
               const int* __restrict__ et, const float* __restrict__ rw,
               const float* __restrict__ deg, float* __restrict__ agg, int E)
{
    long long g = (long long)blockIdx.x * 256 + threadIdx.x;
    int e = (int)(g >> 6);
    int lane = (int)(g & 63);
    if (e >= E) return;
    int row = ei[e];
    int col = ei[E + e];
    float w = lrelu(rw[et[e]] * 100.f);
    float ew = w / fabsf(deg[col]);
    const float2 v = *(const float2*)(src + (size_t)row * HID + lane * 2);
    float* d = agg + (size_t)col * HID + lane * 2;
    atomicAdd(d, ew * v.x);
    atomicAdd(d + 1, ew * v.y);
}

// out[m][n] = X[m] @ W[:,n] + bias[n] (+ resid[m][n])
template<int NOUT, bool RESID>
__global__ __launch_bounds__(256)
void k_gemm_plain(const float* __restrict__ X, const float* __restrict__ W,
                  const float* __restrict__ bias, const float* __restrict__ resid,
                  float* __restrict__ out, int M)
{
    __shared__ float tile[64 * HID];
    int base = blockIdx.x * 64;
    int t = threadIdx.x;
    int rows = M - base; if (rows > 64) rows = 64;
    for (int flat = t; flat < 64 * HID; flat += 256) {
        int r = flat >> 7;
        tile[flat] = (r < rows) ? X[(size_t)base * HID + flat] : 0.f;
    }
    __syncthreads();
    int nl = t & 31, mg = t >> 5;
    for (int nb = 0; nb < NOUT; nb += 128) {
        float acc[8][4];
#pragma unroll
        for (int m = 0; m < 8; m++)
#pragma unroll
            for (int c = 0; c < 4; c++) acc[m][c] = 0.f;
        int ncol[4];
#pragma unroll
        for (int c = 0; c < 4; c++) {
            int n = nb + nl + 32 * c;
            ncol[c] = (n < NOUT) ? n : (NOUT - 1);
        }
        for (int k = 0; k < HID; k++) {
            float w[4];
#pragma unroll
            for (int c = 0; c < 4; c++) w[c] = W[k * NOUT + ncol[c]];
#pragma unroll
            for (int m = 0; m < 8; m++) {
                float xm = tile[(mg * 8 + m) * HID + k];
#pragma unroll
                for (int c = 0; c < 4; c++) acc[m][c] += xm * w[c];
            }
        }
#pragma unroll
        for (int m = 0; m < 8; m++) {
            int r = mg * 8 + m;
            if (r >= rows) continue;
            size_t orow = (size_t)(base + r);
#pragma unroll
            for (int c = 0; c < 4; c++) {
                int n = nb + nl + 32 * c;
                if (n < NOUT) {
                    float v = acc[m][c] + bias[n];
                    if (RESID) v += resid[orow * HID + n];
                    out[orow * NOUT + n] = v;
                }
            }
        }
    }
}

__global__ __launch_bounds__(256)
void k_bn_stats(const float* __restrict__ x, float* __restrict__ sums, int M)
{
    int c = threadIdx.x & 127;
    int rr = threadIdx.x >> 7;
    float s = 0.f, s2 = 0.f;
    for (int r = blockIdx.x * 2 + rr; r < M; r += gridDim.x * 2) {
        float v = x[(size_t)r * HID + c];
        s += v; s2 += v * v;
    }
    atomicAdd(&sums[c], s);
    atomicAdd(&sums[HID + c], s2);
}

__global__
void k_bn_finalize(const float* __restrict__ sums, const float* __restrict__ g,
                   const float* __restrict__ b, float* __restrict__ coef, int M)
{
    int c = threadIdx.x;  // 128 threads
    float inv = 1.f / (float)M;
    float mean = sums[c] * inv;
    float var = sums[HID + c] * inv - mean * mean;
    float sc = g[c] * rsqrtf(var + BN_EPS);
    coef[c] = sc;
    coef[HID + c] = b[c] - mean * sc;
}

__global__ __launch_bounds__(256)
void k_bn_apply(const float* __restrict__ x, const float* __restrict__ coef,
                const float* __restrict__ pa, float* __restrict__ out, int M)
{
    float a = pa[0];
    int n4 = M * (HID / 4);
    for (int i = blockIdx.x * blockDim.x + threadIdx.x; i < n4;
         i += gridDim.x * blockDim.x) {
        int c4 = (i & 31) * 4;
        float4 v = ((const float4*)x)[i];
        float4 o;
        float* vv = (float*)&v;
        float* oo = (float*)&o;
#pragma unroll
        for (int j = 0; j < 4; j++) {
            int c = c4 + j;
            float u = vv[j] * coef[c] + coef[HID + c];
            oo[j] = u >= 0.f ? u : a * u;
        }
        ((float4*)out)[i] = o;
    }
}

__global__ __launch_bounds__(256)
void k_logsoftmax(float* __restrict__ out, int M)
{
    int wid = (int)((blockIdx.x * 256 + threadIdx.x) >> 6);
    int lane = threadIdx.x & 63;
    if (wid >= M) return;
    float* row = out + (size_t)wid * NCLS;
    float mx = -1e30f;
    for (int c = lane; c < NCLS; c += 64) mx = fmaxf(mx, row[c]);
#pragma unroll
    for (int off = 32; off > 0; off >>= 1) mx = fmaxf(mx, __shfl_xor(mx, off));
    float s = 0.f;
    for (int c = lane; c < NCLS; c += 64) s += expf(row[c] - mx);
#pragma unroll
    for (int off = 32; off > 0; off >>= 1) s += __shfl_xor(s, off);
    float lse = mx + logf(s);
    for (int c = lane; c < NCLS; c += 64) row[c] -= lse;
}

extern "C" void kernel_launch(void* const* d_in, const int* in_sizes, int n_in,
                              void* d_out, int out_size, void* d_ws, size_t ws_size,
                              hipStream_t stream)
{
    const float* x0      = (const float*)d_in[0];
    const float* x1      = (const float*)d_in[1];
    const int*   ei      = (const int*)d_in[2];
    const int*   et      = (const int*)d_in[3];
    const int*   ntype   = (const int*)d_in[4];
    const int*   lni     = (const int*)d_in[5];
    const float* lin0_w  = (const float*)d_in[6];
    const float* lin0_b  = (const float*)d_in[7];
    const float* lin1_w  = (const float*)d_in[8];
    const float* lin1_b  = (const float*)d_in[9];
    const float* conv0_w = (const float*)d_in[10];
    const float* conv0_b = (const float*)d_in[11];
    const float* conv0_rw= (const float*)d_in[12];
    const float* conv1_w = (const float*)d_in[13];
    const float* conv1_b = (const float*)d_in[14];
    const float* conv1_rw= (const float*)d_in[15];
    const float* bn_g    = (const float*)d_in[16];
    const float* bn_b    = (const float*)d_in[17];
    const float* pa      = (const float*)d_in[18];

    int E = in_sizes[2] / 2;
    int M = in_sizes[4];

    float* ws = (float*)d_ws;
    size_t mh = (size_t)M * HID;
    float* A       = ws;            // h, later xbn
    float* B       = A + mh;        // agg0 / agg1 accumulator
    float* C       = (float*)d_out; // x after layer0 (aliases d_out; dead before final GEMM)
    float* deg0    = B + mh;
    float* deg1    = deg0 + M;
    float* bn_sums = deg1 + M;      // 256
    float* bn_coef = bn_sums + 256; // 256
    int*   cnt     = (int*)(bn_coef + 256); // 2
    int*   lists   = cnt + 2;               // 2*M

    // zero accumulators (ws is poisoned before every launch)
    hipMemsetAsync(B, 0, mh * sizeof(float), stream);
    hipMemsetAsync(deg0, 0, (size_t)(2 * M + 512) * sizeof(float) + 2 * sizeof(int), stream);

    k_edge_deg<<<(E + 255) / 256, 256, 0, stream>>>(ei, et, conv0_rw, conv1_rw, deg0, deg1, E);
    k_compact<<<(M + 255) / 256, 256, 0, stream>>>(ntype, cnt, lists, M);

    int gblocks = (M + 63) / 64;
    k_gemm_group<<<gblocks, 256, 0, stream>>>(x0, lin0_w, lin0_b, lists,     lni, cnt,     A);
    k_gemm_group<<<gblocks, 256, 0, stream>>>(x1, lin1_w, lin1_b, lists + M, lni, cnt + 1, A);

    long long sth = (long long)E * 64;
    int sblocks = (int)((sth + 255) / 256);
    k_scatter<<<sblocks, 256, 0, stream>>>(A, ei, et, conv0_rw, deg0, B, E);

    k_gemm_plain<HID, true><<<gblocks, 256, 0, stream>>>(B, conv0_w, conv0_b, A, C, M);

    k_bn_stats<<<512, 256, 0, stream>>>(C, bn_sums, M);
    k_bn_finalize<<<1, 128, 0, stream>>>(bn_sums, bn_g, bn_b, bn_coef, M);
    k_bn_apply<<<2048, 256, 0, stream>>>(C, bn_coef, pa, A, M);

    hipMemsetAsync(B, 0, mh * sizeof(float), stream);
    k_scatter<<<sblocks, 256, 0, stream>>>(A, ei, et, conv1_rw, deg1, B, E);

    k_gemm_plain<NCLS, false><<<gblocks, 256, 0, stream>>>(B, conv1_w, conv1_b, nullptr, (float*)d_out, M);
    k_logsoftmax<<<(M + 3) / 4, 256, 0, stream>>>((float*)d_out, M);
}

// Round 3
// 1605.523 us; speedup vs baseline: 1.4765x; 1.4765x over previous
//
#include <hip/hip_runtime.h>
#include <math.h>

#define HID 128
#define NCLS 349
#define BN_EPS 1e-5f

__device__ __forceinline__ float lrelu(float v){ return v >= 0.f ? v : 0.01f*v; }

__global__ __launch_bounds__(256)
void k_edge_deg(const int* __restrict__ ei, const int* __restrict__ et,
                const float* __restrict__ rw0, const float* __restrict__ rw1,
                float* __restrict__ deg0, float* __restrict__ deg1, int E)
{
    int e = blockIdx.x * 256 + threadIdx.x;
    if (e >= E) return;
    int col = ei[E + e];
    int t = et[e];
    atomicAdd(deg0 + col, lrelu(rw0[t] * 100.f));
    atomicAdd(deg1 + col, lrelu(rw1[t] * 100.f));
}

// wave-ballot + block-aggregated two-way partition: 2 global atomics per block
__global__ __launch_bounds__(256)
void k_compact(const int* __restrict__ node_type, int* __restrict__ cnt,
               int* __restrict__ lists, int M)
{
    __shared__ int wcnt[4][2];
    __shared__ int bbase[2];
    int tid = threadIdx.x;
    int wid = tid >> 6, lane = tid & 63;
    int i = blockIdx.x * 256 + tid;
    bool valid = i < M;
    int t = valid ? (node_type[i] & 1) : -1;
    unsigned long long m0 = __ballot(t == 0);
    unsigned long long m1 = __ballot(t == 1);
    if (lane == 0) { wcnt[wid][0] = __popcll(m0); wcnt[wid][1] = __popcll(m1); }
    __syncthreads();
    if (tid == 0) {
        int s0 = wcnt[0][0] + wcnt[1][0] + wcnt[2][0] + wcnt[3][0];
        int s1 = wcnt[0][1] + wcnt[1][1] + wcnt[2][1] + wcnt[3][1];
        bbase[0] = atomicAdd(cnt + 0, s0);
        bbase[1] = atomicAdd(cnt + 1, s1);
    }
    __syncthreads();
    int w0 = bbase[0], w1 = bbase[1];
    for (int w = 0; w < wid; w++) { w0 += wcnt[w][0]; w1 += wcnt[w][1]; }
    unsigned long long below = (1ull << lane) - 1ull;
    if (t == 0)      lists[w0 + __popcll(m0 & below)] = i;
    else if (t == 1) lists[M + w1 + __popcll(m1 & below)] = i;
}

// gathered GEMM: out[list[g]] = Xsrc[lni[list[g]]] @ W + b   (K = N = 128)
__global__ __launch_bounds__(256)
void k_gemm_group(const float* __restrict__ Xsrc, const float* __restrict__ W,
                  const float* __restrict__ bias, const int* __restrict__ list,
                  const int* __restrict__ lni, const int* __restrict__ cntp,
                  float* __restrict__ out)
{
    __shared__ float tile[64 * HID];
    __shared__ int outrow[64];
    __shared__ int srcrow[64];
    int cnt = *cntp;
    int base = blockIdx.x * 64;
    if (base >= cnt) return;
    int t = threadIdx.x;
    if (t < 64) {
        int g = base + t;
        int node = (g < cnt) ? list[g] : -1;
        outrow[t] = node;
        srcrow[t] = (node >= 0) ? lni[node] : 0;
    }
    __syncthreads();
    for (int flat = t; flat < 64 * HID; flat += 256) {
        int r = flat >> 7;
        int c = flat & 127;
        tile[flat] = (outrow[r] >= 0) ? Xsrc[(size_t)srcrow[r] * HID + c] : 0.f;
    }
    __syncthreads();
    int nl = t & 31, mg = t >> 5;
    float acc[8][4];
#pragma unroll
    for (int m = 0; m < 8; m++)
#pragma unroll
        for (int c = 0; c < 4; c++) acc[m][c] = 0.f;
    for (int k = 0; k < HID; k++) {
        float w[4];
#pragma unroll
        for (int c = 0; c < 4; c++) w[c] = W[k * HID + nl + 32 * c];
#pragma unroll
        for (int m = 0; m < 8; m++) {
            float xm = tile[(mg * 8 + m) * HID + k];
#pragma unroll
            for (int c = 0; c < 4; c++) acc[m][c] += xm * w[c];
        }
    }
#pragma unroll
    for (int m = 0; m < 8; m++) {
        int r = mg * 8 + m;
        int node = outrow[r];
        if (node < 0) continue;
#pragma unroll
        for (int c = 0; c < 4; c++) {
            int n = nl + 32 * c;
            out[(size_t)node * HID + n] = acc[m][c] + bias[n];
        }
    }
}

// agg[col] += (w_rel / |deg[col]|) * src[row]   -- one wave per edge, 2 ch/lane
__global__ __launch_bounds__(256)
void k_scatter(const float* __restrict__ src, const int* __restrict__ ei,
               const int* __restrict__ et, const float* __restrict__ rw,
               const float* __restrict__ deg, float* __restrict__ agg, int E)
{
    long long g = (long long)blockIdx.x * 256 + threadIdx.x;
    int e = (int)(g >> 6);
    int lane = (int)(g & 63);
    if (e >= E) return;
    int row = ei[e];
    int col = ei[E + e];
    float w = lrelu(rw[et[e]] * 100.f);
    float ew = w / fabsf(deg[col]);
    const float2 v = *(const float2*)(src + (size_t)row * HID + lane * 2);
    float* d = agg + (size_t)col * HID + lane * 2;
    atomicAdd(d, ew * v.x);
    atomicAdd(d + 1, ew * v.y);
}

// out[m][n] = X[m] @ W[:,n] + bias[n] (+ resid[m][n])
template<int NOUT, bool RESID>
__global__ __launch_bounds__(256)
void k_gemm_plain(const float* __restrict__ X, const float* __restrict__ W,
                  const float* __restrict__ bias, const float* __restrict__ resid,
                  float* __restrict__ out, int M)
{
    __shared__ float tile[64 * HID];
    int base = blockIdx.x * 64;
    int t = threadIdx.x;
    int rows = M - base; if (rows > 64) rows = 64;
    for (int flat = t; flat < 64 * HID; flat += 256) {
        int r = flat >> 7;
        tile[flat] = (r < rows) ? X[(size_t)base * HID + flat] : 0.f;
    }
    __syncthreads();
    int nl = t & 31, mg = t >> 5;
    for (int nb = 0; nb < NOUT; nb += 128) {
        float acc[8][4];
#pragma unroll
        for (int m = 0; m < 8; m++)
#pragma unroll
            for (int c = 0; c < 4; c++) acc[m][c] = 0.f;
        int ncol[4];
#pragma unroll
        for (int c = 0; c < 4; c++) {
            int n = nb + nl + 32 * c;
            ncol[c] = (n < NOUT) ? n : (NOUT - 1);
        }
        for (int k = 0; k < HID; k++) {
            float w[4];
#pragma unroll
            for (int c = 0; c < 4; c++) w[c] = W[k * NOUT + ncol[c]];
#pragma unroll
            for (int m = 0; m < 8; m++) {
                float xm = tile[(mg * 8 + m) * HID + k];
#pragma unroll
                for (int c = 0; c < 4; c++) acc[m][c] += xm * w[c];
            }
        }
#pragma unroll
        for (int m = 0; m < 8; m++) {
            int r = mg * 8 + m;
            if (r >= rows) continue;
            size_t orow = (size_t)(base + r);
#pragma unroll
            for (int c = 0; c < 4; c++) {
                int n = nb + nl + 32 * c;
                if (n < NOUT) {
                    float v = acc[m][c] + bias[n];
                    if (RESID) v += resid[orow * HID + n];
                    out[orow * NOUT + n] = v;
                }
            }
        }
    }
}

__global__ __launch_bounds__(256)
void k_bn_stats(const float* __restrict__ x, float* __restrict__ sums, int M)
{
    int c = threadIdx.x & 127;
    int rr = threadIdx.x >> 7;
    float s = 0.f, s2 = 0.f;
    for (int r = blockIdx.x * 2 + rr; r < M; r += gridDim.x * 2) {
        float v = x[(size_t)r * HID + c];
        s += v; s2 += v * v;
    }
    atomicAdd(&sums[c], s);
    atomicAdd(&sums[HID + c], s2);
}

__global__
void k_bn_finalize(const float* __restrict__ sums, const float* __restrict__ g,
                   const float* __restrict__ b, float* __restrict__ coef, int M)
{
    int c = threadIdx.x;  // 128 threads
    float inv = 1.f / (float)M;
    float mean = sums[c] * inv;
    float var = sums[HID + c] * inv - mean * mean;
    float sc = g[c] * rsqrtf(var + BN_EPS);
    coef[c] = sc;
    coef[HID + c] = b[c] - mean * sc;
}

__global__ __launch_bounds__(256)
void k_bn_apply(const float* __restrict__ x, const float* __restrict__ coef,
                const float* __restrict__ pa, float* __restrict__ out, int M)
{
    float a = pa[0];
    int n4 = M * (HID / 4);
    for (int i = blockIdx.x * blockDim.x + threadIdx.x; i < n4;
         i += gridDim.x * blockDim.x) {
        int c4 = (i & 31) * 4;
        float4 v = ((const float4*)x)[i];
        float4 o;
        float* vv = (float*)&v;
        float* oo = (float*)&o;
#pragma unroll
        for (int j = 0; j < 4; j++) {
            int c = c4 + j;
            float u = vv[j] * coef[c] + coef[HID + c];
            oo[j] = u >= 0.f ? u : a * u;
        }
        ((float4*)out)[i] = o;
    }
}

__global__ __launch_bounds__(256)
void k_logsoftmax(float* __restrict__ out, int M)
{
    int wid = (int)((blockIdx.x * 256 + threadIdx.x) >> 6);
    int lane = threadIdx.x & 63;
    if (wid >= M) return;
    float* row = out + (size_t)wid * NCLS;
    float mx = -1e30f;
    for (int c = lane; c < NCLS; c += 64) mx = fmaxf(mx, row[c]);
#pragma unroll
    for (int off = 32; off > 0; off >>= 1) mx = fmaxf(mx, __shfl_xor(mx, off));
    float s = 0.f;
    for (int c = lane; c < NCLS; c += 64) s += expf(row[c] - mx);
#pragma unroll
    for (int off = 32; off > 0; off >>= 1) s += __shfl_xor(s, off);
    float lse = mx + logf(s);
    for (int c = lane; c < NCLS; c += 64) row[c] -= lse;
}

extern "C" void kernel_launch(void* const* d_in, const int* in_sizes, int n_in,
                              void* d_out, int out_size, void* d_ws, size_t ws_size,
                              hipStream_t stream)
{
    const float* x0      = (const float*)d_in[0];
    const float* x1      = (const float*)d_in[1];
    const int*   ei      = (const int*)d_in[2];
    const int*   et      = (const int*)d_in[3];
    const int*   ntype   = (const int*)d_in[4];
    const int*   lni     = (const int*)d_in[5];
    const float* lin0_w  = (const float*)d_in[6];
    const float* lin0_b  = (const float*)d_in[7];
    const float* lin1_w  = (const float*)d_in[8];
    const float* lin1_b  = (const float*)d_in[9];
    const float* conv0_w = (const float*)d_in[10];
    const float* conv0_b = (const float*)d_in[11];
    const float* conv0_rw= (const float*)d_in[12];
    const float* conv1_w = (const float*)d_in[13];
    const float* conv1_b = (const float*)d_in[14];
    const float* conv1_rw= (const float*)d_in[15];
    const float* bn_g    = (const float*)d_in[16];
    const float* bn_b    = (const float*)d_in[17];
    const float* pa      = (const float*)d_in[18];

    int E = in_sizes[2] / 2;
    int M = in_sizes[4];

    float* ws = (float*)d_ws;
    size_t mh = (size_t)M * HID;
    float* A       = ws;            // h, later xbn
    float* B       = A + mh;        // agg0 / agg1 accumulator
    float* C       = (float*)d_out; // x after layer0 (aliases d_out; dead before final GEMM)
    float* deg0    = B + mh;
    float* deg1    = deg0 + M;
    float* bn_sums = deg1 + M;      // 256
    float* bn_coef = bn_sums + 256; // 256
    int*   cnt     = (int*)(bn_coef + 256); // 2
    int*   lists   = cnt + 2;               // 2*M

    // zero accumulators (ws is poisoned before every launch)
    hipMemsetAsync(B, 0, mh * sizeof(float), stream);
    hipMemsetAsync(deg0, 0, (size_t)(2 * M + 512) * sizeof(float) + 2 * sizeof(int), stream);

    k_edge_deg<<<(E + 255) / 256, 256, 0, stream>>>(ei, et, conv0_rw, conv1_rw, deg0, deg1, E);
    k_compact<<<(M + 255) / 256, 256, 0, stream>>>(ntype, cnt, lists, M);

    int gblocks = (M + 63) / 64;
    k_gemm_group<<<gblocks, 256, 0, stream>>>(x0, lin0_w, lin0_b, lists,     lni, cnt,     A);
    k_gemm_group<<<gblocks, 256, 0, stream>>>(x1, lin1_w, lin1_b, lists + M, lni, cnt + 1, A);

    long long sth = (long long)E * 64;
    int sblocks = (int)((sth + 255) / 256);
    k_scatter<<<sblocks, 256, 0, stream>>>(A, ei, et, conv0_rw, deg0, B, E);

    k_gemm_plain<HID, true><<<gblocks, 256, 0, stream>>>(B, conv0_w, conv0_b, A, C, M);

    k_bn_stats<<<512, 256, 0, stream>>>(C, bn_sums, M);
    k_bn_finalize<<<1, 128, 0, stream>>>(bn_sums, bn_g, bn_b, bn_coef, M);
    k_bn_apply<<<2048, 256, 0, stream>>>(C, bn_coef, pa, A, M);

    hipMemsetAsync(B, 0, mh * sizeof(float), stream);
    k_scatter<<<sblocks, 256, 0, stream>>>(A, ei, et, conv1_rw, deg1, B, E);

    k_gemm_plain<NCLS, false><<<gblocks, 256, 0, stream>>>(B, conv1_w, conv1_b, nullptr, (float*)d_out, M);
    k_logsoftmax<<<(M + 3) / 4, 256, 0, stream>>>((float*)d_out, M);
}

// Round 4
// 877.984 us; speedup vs baseline: 2.7001x; 1.8286x over previous
//
#include <hip/hip_runtime.h>
#include <math.h>

#define HID 128
#define NCLS 349
#define BN_EPS 1e-5f
#define SCAN_CHUNK 1024

__device__ __forceinline__ float lrelu(float v){ return v >= 0.f ? v : 0.01f*v; }

// ---------------- CSR build ----------------

__global__ __launch_bounds__(256)
void k_hist(const int* __restrict__ ei, int* __restrict__ cntE, int E)
{
    int e = blockIdx.x * 256 + threadIdx.x;
    if (e < E) atomicAdd(cntE + ei[E + e], 1);
}

__global__ __launch_bounds__(256)
void k_scan_part(const int* __restrict__ cntE, int* __restrict__ rowptr,
                 int* __restrict__ partials, int M)
{
    __shared__ int sd[256];
    int t = threadIdx.x;
    int base = blockIdx.x * SCAN_CHUNK + t * 4;
    int v[4]; int s = 0;
#pragma unroll
    for (int j = 0; j < 4; j++) { int i = base + j; v[j] = (i < M) ? cntE[i] : 0; s += v[j]; }
    sd[t] = s; __syncthreads();
    for (int off = 1; off < 256; off <<= 1) {
        int x = (t >= off) ? sd[t - off] : 0;
        __syncthreads();
        sd[t] += x;
        __syncthreads();
    }
    int run = sd[t] - s;              // exclusive prefix of this thread's chunk
    if (t == 255) partials[blockIdx.x] = sd[255];
#pragma unroll
    for (int j = 0; j < 4; j++) { int i = base + j; if (i < M) rowptr[i] = run; run += v[j]; }
}

__global__ __launch_bounds__(256)
void k_scan_base(int* __restrict__ partials, int* __restrict__ rowptr_last, int npart)
{
    __shared__ int sd[256];
    int t = threadIdx.x;
    int v = (t < npart) ? partials[t] : 0;
    sd[t] = v; __syncthreads();
    for (int off = 1; off < 256; off <<= 1) {
        int x = (t >= off) ? sd[t - off] : 0;
        __syncthreads();
        sd[t] += x;
        __syncthreads();
    }
    if (t < npart) partials[t] = sd[t] - v;   // exclusive base per chunk
    if (t == 255) rowptr_last[0] = sd[255];   // total = E
}

__global__ __launch_bounds__(256)
void k_scan_add(int* __restrict__ rowptr, const int* __restrict__ partials, int M)
{
    int b = partials[blockIdx.x];
    int base = blockIdx.x * SCAN_CHUNK + threadIdx.x * 4;
#pragma unroll
    for (int j = 0; j < 4; j++) { int i = base + j; if (i < M) rowptr[i] += b; }
}

__global__ __launch_bounds__(256)
void k_fill(const int* __restrict__ ei, const int* __restrict__ et,
            const int* __restrict__ rowptr, int* __restrict__ pos,
            int* __restrict__ packed, int E)
{
    int e = blockIdx.x * 256 + threadIdx.x;
    if (e >= E) return;
    int col = ei[E + e];
    int p = atomicAdd(pos + col, 1);
    packed[rowptr[col] + p] = ei[e] | (et[e] << 20);
}

// ---------------- node-type partition ----------------

__global__ __launch_bounds__(256)
void k_compact(const int* __restrict__ node_type, int* __restrict__ cnt,
               int* __restrict__ lists, int M)
{
    __shared__ int wcnt[4][2];
    __shared__ int bbase[2];
    int tid = threadIdx.x;
    int wid = tid >> 6, lane = tid & 63;
    int i = blockIdx.x * 256 + tid;
    bool valid = i < M;
    int t = valid ? (node_type[i] & 1) : -1;
    unsigned long long m0 = __ballot(t == 0);
    unsigned long long m1 = __ballot(t == 1);
    if (lane == 0) { wcnt[wid][0] = __popcll(m0); wcnt[wid][1] = __popcll(m1); }
    __syncthreads();
    if (tid == 0) {
        int s0 = wcnt[0][0] + wcnt[1][0] + wcnt[2][0] + wcnt[3][0];
        int s1 = wcnt[0][1] + wcnt[1][1] + wcnt[2][1] + wcnt[3][1];
        bbase[0] = atomicAdd(cnt + 0, s0);
        bbase[1] = atomicAdd(cnt + 1, s1);
    }
    __syncthreads();
    int w0 = bbase[0], w1 = bbase[1];
    for (int w = 0; w < wid; w++) { w0 += wcnt[w][0]; w1 += wcnt[w][1]; }
    unsigned long long below = (1ull << lane) - 1ull;
    if (t == 0)      lists[w0 + __popcll(m0 & below)] = i;
    else if (t == 1) lists[M + w1 + __popcll(m1 & below)] = i;
}

// gathered GEMM: out[list[g]] = Xsrc[lni[list[g]]] @ W + b   (K = N = 128)
__global__ __launch_bounds__(256)
void k_gemm_group(const float* __restrict__ Xsrc, const float* __restrict__ W,
                  const float* __restrict__ bias, const int* __restrict__ list,
                  const int* __restrict__ lni, const int* __restrict__ cntp,
                  float* __restrict__ out)
{
    __shared__ float tile[64 * HID];
    __shared__ int outrow[64];
    __shared__ int srcrow[64];
    int cnt = *cntp;
    int base = blockIdx.x * 64;
    if (base >= cnt) return;
    int t = threadIdx.x;
    if (t < 64) {
        int g = base + t;
        int node = (g < cnt) ? list[g] : -1;
        outrow[t] = node;
        srcrow[t] = (node >= 0) ? lni[node] : 0;
    }
    __syncthreads();
    for (int flat = t; flat < 64 * HID; flat += 256) {
        int r = flat >> 7;
        int c = flat & 127;
        tile[flat] = (outrow[r] >= 0) ? Xsrc[(size_t)srcrow[r] * HID + c] : 0.f;
    }
    __syncthreads();
    int nl = t & 31, mg = t >> 5;
    float acc[8][4];
#pragma unroll
    for (int m = 0; m < 8; m++)
#pragma unroll
        for (int c = 0; c < 4; c++) acc[m][c] = 0.f;
    for (int k = 0; k < HID; k++) {
        float w[4];
#pragma unroll
        for (int c = 0; c < 4; c++) w[c] = W[k * HID + nl + 32 * c];
#pragma unroll
        for (int m = 0; m < 8; m++) {
            float xm = tile[(mg * 8 + m) * HID + k];
#pragma unroll
            for (int c = 0; c < 4; c++) acc[m][c] += xm * w[c];
        }
    }
#pragma unroll
    for (int m = 0; m < 8; m++) {
        int r = mg * 8 + m;
        int node = outrow[r];
        if (node < 0) continue;
#pragma unroll
        for (int c = 0; c < 4; c++) {
            int n = nl + 32 * c;
            out[(size_t)node * HID + n] = acc[m][c] + bias[n];
        }
    }
}

// CSR gather-aggregate: out[n] = (sum_e w_e * src[row_e]) / |sum_e w_e|
// one wave per node, 2 channels per lane
__global__ __launch_bounds__(256)
void k_gather(const float* __restrict__ src, const int* __restrict__ rowptr,
              const int* __restrict__ packed, const float* __restrict__ rw,
              float* __restrict__ out, int M)
{
    __shared__ float lut[8];
    int t = threadIdx.x;
    if (t < 8) lut[t] = lrelu(rw[t] * 100.f);
    __syncthreads();
    int wid = t >> 6, lane = t & 63;
    int n = blockIdx.x * 4 + wid;
    if (n >= M) return;
    int e0 = rowptr[n], e1 = rowptr[n + 1];
    float ax = 0.f, ay = 0.f, wsum = 0.f;
    for (int e = e0; e < e1; e++) {
        int p = packed[e];
        int row = p & 0xFFFFF;
        float w = lut[p >> 20];
        float2 v = *(const float2*)(src + (size_t)row * HID + lane * 2);
        ax += w * v.x; ay += w * v.y;
        wsum += w;
    }
    float inv = (wsum != 0.f) ? 1.f / fabsf(wsum) : 0.f;
    float2 o; o.x = ax * inv; o.y = ay * inv;
    *(float2*)(out + (size_t)n * HID + lane * 2) = o;
}

// out[m][n] = X[m] @ W[:,n] + bias[n] (+ resid[m][n])
template<int NOUT, bool RESID>
__global__ __launch_bounds__(256)
void k_gemm_plain(const float* __restrict__ X, const float* __restrict__ W,
                  const float* __restrict__ bias, const float* __restrict__ resid,
                  float* __restrict__ out, int M)
{
    __shared__ float tile[64 * HID];
    int base = blockIdx.x * 64;
    int t = threadIdx.x;
    int rows = M - base; if (rows > 64) rows = 64;
    for (int flat = t; flat < 64 * HID; flat += 256) {
        int r = flat >> 7;
        tile[flat] = (r < rows) ? X[(size_t)base * HID + flat] : 0.f;
    }
    __syncthreads();
    int nl = t & 31, mg = t >> 5;
    for (int nb = 0; nb < NOUT; nb += 128) {
        float acc[8][4];
#pragma unroll
        for (int m = 0; m < 8; m++)
#pragma unroll
            for (int c = 0; c < 4; c++) acc[m][c] = 0.f;
        int ncol[4];
#pragma unroll
        for (int c = 0; c < 4; c++) {
            int n = nb + nl + 32 * c;
            ncol[c] = (n < NOUT) ? n : (NOUT - 1);
        }
        for (int k = 0; k < HID; k++) {
            float w[4];
#pragma unroll
            for (int c = 0; c < 4; c++) w[c] = W[k * NOUT + ncol[c]];
#pragma unroll
            for (int m = 0; m < 8; m++) {
                float xm = tile[(mg * 8 + m) * HID + k];
#pragma unroll
                for (int c = 0; c < 4; c++) acc[m][c] += xm * w[c];
            }
        }
#pragma unroll
        for (int m = 0; m < 8; m++) {
            int r = mg * 8 + m;
            if (r >= rows) continue;
            size_t orow = (size_t)(base + r);
#pragma unroll
            for (int c = 0; c < 4; c++) {
                int n = nb + nl + 32 * c;
                if (n < NOUT) {
                    float v = acc[m][c] + bias[n];
                    if (RESID) v += resid[orow * HID + n];
                    out[orow * NOUT + n] = v;
                }
            }
        }
    }
}

__global__ __launch_bounds__(256)
void k_bn_stats(const float* __restrict__ x, float* __restrict__ sums, int M)
{
    int c = threadIdx.x & 127;
    int rr = threadIdx.x >> 7;
    float s = 0.f, s2 = 0.f;
    for (int r = blockIdx.x * 2 + rr; r < M; r += gridDim.x * 2) {
        float v = x[(size_t)r * HID + c];
        s += v; s2 += v * v;
    }
    atomicAdd(&sums[c], s);
    atomicAdd(&sums[HID + c], s2);
}

__global__
void k_bn_finalize(const float* __restrict__ sums, const float* __restrict__ g,
                   const float* __restrict__ b, float* __restrict__ coef, int M)
{
    int c = threadIdx.x;  // 128 threads
    float inv = 1.f / (float)M;
    float mean = sums[c] * inv;
    float var = sums[HID + c] * inv - mean * mean;
    float sc = g[c] * rsqrtf(var + BN_EPS);
    coef[c] = sc;
    coef[HID + c] = b[c] - mean * sc;
}

__global__ __launch_bounds__(256)
void k_bn_apply(const float* __restrict__ x, const float* __restrict__ coef,
                const float* __restrict__ pa, float* __restrict__ out, int M)
{
    float a = pa[0];
    int n4 = M * (HID / 4);
    for (int i = blockIdx.x * blockDim.x + threadIdx.x; i < n4;
         i += gridDim.x * blockDim.x) {
        int c4 = (i & 31) * 4;
        float4 v = ((const float4*)x)[i];
        float4 o;
        float* vv = (float*)&v;
        float* oo = (float*)&o;
#pragma unroll
        for (int j = 0; j < 4; j++) {
            int c = c4 + j;
            float u = vv[j] * coef[c] + coef[HID + c];
            oo[j] = u >= 0.f ? u : a * u;
        }
        ((float4*)out)[i] = o;
    }
}

// register-cached log-softmax: 1 read + 1 write per element
__global__ __launch_bounds__(256)
void k_logsoftmax(float* __restrict__ out, int M)
{
    int wid = (int)((blockIdx.x * 256 + threadIdx.x) >> 6);
    int lane = threadIdx.x & 63;
    if (wid >= M) return;
    float* row = out + (size_t)wid * NCLS;
    float rv[6];
    float mx = -1e30f;
#pragma unroll
    for (int k = 0; k < 6; k++) {
        int c = lane + k * 64;
        rv[k] = (c < NCLS) ? row[c] : -1e30f;
        mx = fmaxf(mx, rv[k]);
    }
#pragma unroll
    for (int off = 32; off > 0; off >>= 1) mx = fmaxf(mx, __shfl_xor(mx, off));
    float s = 0.f;
#pragma unroll
    for (int k = 0; k < 6; k++) {
        int c = lane + k * 64;
        if (c < NCLS) s += expf(rv[k] - mx);
    }
#pragma unroll
    for (int off = 32; off > 0; off >>= 1) s += __shfl_xor(s, off);
    float lse = mx + logf(s);
#pragma unroll
    for (int k = 0; k < 6; k++) {
        int c = lane + k * 64;
        if (c < NCLS) row[c] = rv[k] - lse;
    }
}

extern "C" void kernel_launch(void* const* d_in, const int* in_sizes, int n_in,
                              void* d_out, int out_size, void* d_ws, size_t ws_size,
                              hipStream_t stream)
{
    const float* x0      = (const float*)d_in[0];
    const float* x1      = (const float*)d_in[1];
    const int*   ei      = (const int*)d_in[2];
    const int*   et      = (const int*)d_in[3];
    const int*   ntype   = (const int*)d_in[4];
    const int*   lni     = (const int*)d_in[5];
    const float* lin0_w  = (const float*)d_in[6];
    const float* lin0_b  = (const float*)d_in[7];
    const float* lin1_w  = (const float*)d_in[8];
    const float* lin1_b  = (const float*)d_in[9];
    const float* conv0_w = (const float*)d_in[10];
    const float* conv0_b = (const float*)d_in[11];
    const float* conv0_rw= (const float*)d_in[12];
    const float* conv1_w = (const float*)d_in[13];
    const float* conv1_b = (const float*)d_in[14];
    const float* conv1_rw= (const float*)d_in[15];
    const float* bn_g    = (const float*)d_in[16];
    const float* bn_b    = (const float*)d_in[17];
    const float* pa      = (const float*)d_in[18];

    int E = in_sizes[2] / 2;
    int M = in_sizes[4];

    float* ws = (float*)d_ws;
    size_t mh = (size_t)M * HID;
    float* A       = ws;                    // h / xbn
    float* B       = A + mh;                // agg buffer
    float* C       = (float*)d_out;         // x after layer0 (dead before final GEMM)
    int*   rowptr  = (int*)(B + mh);        // M+1
    int*   packed  = rowptr + (M + 1);      // E   (row | et<<20)
    float* bn_sums = (float*)(packed + E);  // 256
    float* bn_coef = bn_sums + 256;         // 256
    int*   cnt     = (int*)(bn_coef + 256); // 2
    int*   partials= cnt + 2;               // 256
    // overlays (dead before their regions' first real write):
    int*   cntE    = (int*)A;               // M ints: hist counters, then fill position counters
    int*   lists   = (int*)B;               // 2*M ints: type-partition lists

    int npart = (M + SCAN_CHUNK - 1) / SCAN_CHUNK;   // 98 for M=100k (must be <=256)

    // zero hist counters + small control area
    hipMemsetAsync(cntE, 0, (size_t)M * sizeof(int), stream);
    hipMemsetAsync(bn_sums, 0, 512 * sizeof(float) + (2 + 256) * sizeof(int), stream);

    // CSR build (shared by both conv layers)
    k_hist<<<(E + 255) / 256, 256, 0, stream>>>(ei, cntE, E);
    k_scan_part<<<npart, 256, 0, stream>>>(cntE, rowptr, partials, M);
    k_scan_base<<<1, 256, 0, stream>>>(partials, rowptr + M, npart);
    k_scan_add<<<npart, 256, 0, stream>>>(rowptr, partials, M);
    hipMemsetAsync(cntE, 0, (size_t)M * sizeof(int), stream);
    k_fill<<<(E + 255) / 256, 256, 0, stream>>>(ei, et, rowptr, cntE, packed, E);

    // grouped input linear
    k_compact<<<(M + 255) / 256, 256, 0, stream>>>(ntype, cnt, lists, M);
    int gblocks = (M + 63) / 64;
    k_gemm_group<<<gblocks, 256, 0, stream>>>(x0, lin0_w, lin0_b, lists,     lni, cnt,     A);
    k_gemm_group<<<gblocks, 256, 0, stream>>>(x1, lin1_w, lin1_b, lists + M, lni, cnt + 1, A);

    // layer 0: gather-aggregate, then GEMM(+residual)
    k_gather<<<(M + 3) / 4, 256, 0, stream>>>(A, rowptr, packed, conv0_rw, B, M);
    k_gemm_plain<HID, true><<<gblocks, 256, 0, stream>>>(B, conv0_w, conv0_b, A, C, M);

    // BN + PReLU
    k_bn_stats<<<512, 256, 0, stream>>>(C, bn_sums, M);
    k_bn_finalize<<<1, 128, 0, stream>>>(bn_sums, bn_g, bn_b, bn_coef, M);
    k_bn_apply<<<2048, 256, 0, stream>>>(C, bn_coef, pa, A, M);

    // layer 1: gather-aggregate, final GEMM into d_out, log-softmax
    k_gather<<<(M + 3) / 4, 256, 0, stream>>>(A, rowptr, packed, conv1_rw, B, M);
    k_gemm_plain<NCLS, false><<<gblocks, 256, 0, stream>>>(B, conv1_w, conv1_b, nullptr, (float*)d_out, M);
    k_logsoftmax<<<(M + 3) / 4, 256, 0, stream>>>((float*)d_out, M);
}

// Round 5
// 677.649 us; speedup vs baseline: 3.4983x; 1.2956x over previous
//
#include <hip/hip_runtime.h>
#include <math.h>

#define HID 128
#define NCLS 349
#define BN_EPS 1e-5f
#define SCAN_CHUNK 1024

typedef __attribute__((ext_vector_type(8))) short bf16x8;
typedef __attribute__((ext_vector_type(4))) float f32x4;

__device__ __forceinline__ float lrelu(float v){ return v >= 0.f ? v : 0.01f*v; }

__device__ __forceinline__ unsigned short f2bf(float f){
    unsigned u = __float_as_uint(f);
    u += 0x7FFF + ((u >> 16) & 1);           // RNE
    return (unsigned short)(u >> 16);
}
__device__ __forceinline__ float bf2f(unsigned short s){
    return __uint_as_float(((unsigned)s) << 16);
}

// ---------------- CSR build ----------------

__global__ __launch_bounds__(256)
void k_hist(const int* __restrict__ ei, int* __restrict__ cntE, int E)
{
    int e = blockIdx.x * 256 + threadIdx.x;
    if (e < E) atomicAdd(cntE + ei[E + e], 1);
}

__global__ __launch_bounds__(256)
void k_scan_part(const int* __restrict__ cntE, int* __restrict__ rowptr,
                 int* __restrict__ partials, int M)
{
    __shared__ int sd[256];
    int t = threadIdx.x;
    int base = blockIdx.x * SCAN_CHUNK + t * 4;
    int v[4]; int s = 0;
#pragma unroll
    for (int j = 0; j < 4; j++) { int i = base + j; v[j] = (i < M) ? cntE[i] : 0; s += v[j]; }
    sd[t] = s; __syncthreads();
    for (int off = 1; off < 256; off <<= 1) {
        int x = (t >= off) ? sd[t - off] : 0;
        __syncthreads();
        sd[t] += x;
        __syncthreads();
    }
    int run = sd[t] - s;
    if (t == 255) partials[blockIdx.x] = sd[255];
#pragma unroll
    for (int j = 0; j < 4; j++) { int i = base + j; if (i < M) rowptr[i] = run; run += v[j]; }
}

__global__ __launch_bounds__(256)
void k_scan_base(int* __restrict__ partials, int* __restrict__ rowptr_last, int npart)
{
    __shared__ int sd[256];
    int t = threadIdx.x;
    int v = (t < npart) ? partials[t] : 0;
    sd[t] = v; __syncthreads();
    for (int off = 1; off < 256; off <<= 1) {
        int x = (t >= off) ? sd[t - off] : 0;
        __syncthreads();
        sd[t] += x;
        __syncthreads();
    }
    if (t < npart) partials[t] = sd[t] - v;
    if (t == 255) rowptr_last[0] = sd[255];
}

__global__ __launch_bounds__(256)
void k_scan_add(int* __restrict__ rowptr, const int* __restrict__ partials, int M)
{
    int b = partials[blockIdx.x];
    int base = blockIdx.x * SCAN_CHUNK + threadIdx.x * 4;
#pragma unroll
    for (int j = 0; j < 4; j++) { int i = base + j; if (i < M) rowptr[i] += b; }
}

__global__ __launch_bounds__(256)
void k_fill(const int* __restrict__ ei, const int* __restrict__ et,
            const int* __restrict__ rowptr, int* __restrict__ pos,
            int* __restrict__ packed, int E)
{
    int e = blockIdx.x * 256 + threadIdx.x;
    if (e >= E) return;
    int col = ei[E + e];
    int p = atomicAdd(pos + col, 1);
    packed[rowptr[col] + p] = ei[e] | (et[e] << 20);
}

// ---------------- node-type partition ----------------

__global__ __launch_bounds__(256)
void k_compact(const int* __restrict__ node_type, int* __restrict__ cnt,
               int* __restrict__ lists, int M)
{
    __shared__ int wcnt[4][2];
    __shared__ int bbase[2];
    int tid = threadIdx.x;
    int wid = tid >> 6, lane = tid & 63;
    int i = blockIdx.x * 256 + tid;
    bool valid = i < M;
    int t = valid ? (node_type[i] & 1) : -1;
    unsigned long long m0 = __ballot(t == 0);
    unsigned long long m1 = __ballot(t == 1);
    if (lane == 0) { wcnt[wid][0] = __popcll(m0); wcnt[wid][1] = __popcll(m1); }
    __syncthreads();
    if (tid == 0) {
        int s0 = wcnt[0][0] + wcnt[1][0] + wcnt[2][0] + wcnt[3][0];
        int s1 = wcnt[0][1] + wcnt[1][1] + wcnt[2][1] + wcnt[3][1];
        bbase[0] = atomicAdd(cnt + 0, s0);
        bbase[1] = atomicAdd(cnt + 1, s1);
    }
    __syncthreads();
    int w0 = bbase[0], w1 = bbase[1];
    for (int w = 0; w < wid; w++) { w0 += wcnt[w][0]; w1 += wcnt[w][1]; }
    unsigned long long below = (1ull << lane) - 1ull;
    if (t == 0)      lists[w0 + __popcll(m0 & below)] = i;
    else if (t == 1) lists[M + w1 + __popcll(m1 & below)] = i;
}

// ---------------- weight prep: Wt[col][k] = bf16(W[k][col]), zero-padded cols ----------------

__global__ __launch_bounds__(256)
void k_prep_wt(const float* __restrict__ W, unsigned short* __restrict__ Wt,
               int NCOLS, int NPAD)
{
    int idx = blockIdx.x * 256 + threadIdx.x;
    if (idx >= NPAD * HID) return;
    int col = idx >> 7, k = idx & 127;
    float v = (col < NCOLS) ? W[k * NCOLS + col] : 0.f;
    Wt[idx] = f2bf(v);
}

// ---------------- MFMA GEMMs (16x16x32 bf16, fp32 accum) ----------------
// A/B frag k-map: k = 8*(lane>>4)+j for BOTH operands (same bijection -> correct).
// C/D (m89-verified): col = lane&15, row = (lane>>4)*4 + reg.

// grouped input linear: h[list[g]] = bf16( Xsrc[lni[list[g]]] @ W + b )
__global__ __launch_bounds__(256)
void k_gemm_group_mfma(const float* __restrict__ Xsrc, const unsigned short* __restrict__ Wt,
                       const float* __restrict__ bias, const int* __restrict__ list,
                       const int* __restrict__ lni, const int* __restrict__ cntp,
                       unsigned short* __restrict__ out)
{
    int cnt = *cntp;
    int base = blockIdx.x * 64;
    if (base >= cnt) return;
    int tid = threadIdx.x, w = tid >> 6, l = tid & 63, lr = l & 15, lg = l >> 4;
    int ga = base + w * 16 + lr;
    int node_a = (ga < cnt) ? list[ga] : -1;
    int srow = (node_a >= 0) ? lni[node_a] : 0;
    const float* xp = Xsrc + (size_t)srow * HID + lg * 8;
    bf16x8 afrag[4];
#pragma unroll
    for (int kk = 0; kk < 4; kk++) {
        float4 v0 = *(const float4*)(xp + kk * 32);
        float4 v1 = *(const float4*)(xp + kk * 32 + 4);
        if (node_a < 0) { v0 = make_float4(0,0,0,0); v1 = v0; }
        union { bf16x8 v; short s[8]; } u;
        u.s[0] = (short)f2bf(v0.x); u.s[1] = (short)f2bf(v0.y);
        u.s[2] = (short)f2bf(v0.z); u.s[3] = (short)f2bf(v0.w);
        u.s[4] = (short)f2bf(v1.x); u.s[5] = (short)f2bf(v1.y);
        u.s[6] = (short)f2bf(v1.z); u.s[7] = (short)f2bf(v1.w);
        afrag[kk] = u.v;
    }
    f32x4 acc[8];
#pragma unroll
    for (int nt = 0; nt < 8; nt++) acc[nt] = (f32x4){0.f,0.f,0.f,0.f};
    const unsigned short* wp = Wt + (size_t)lr * HID + lg * 8;
#pragma unroll
    for (int nt = 0; nt < 8; nt++) {
        const unsigned short* wq = wp + nt * 16 * HID;
#pragma unroll
        for (int kk = 0; kk < 4; kk++) {
            bf16x8 bfrag = *(const bf16x8*)(wq + kk * 32);
            acc[nt] = __builtin_amdgcn_mfma_f32_16x16x32_bf16(afrag[kk], bfrag, acc[nt], 0, 0, 0);
        }
    }
#pragma unroll
    for (int r = 0; r < 4; r++) {
        int go = base + w * 16 + lg * 4 + r;
        if (go >= cnt) continue;
        int node = list[go];
        unsigned short* op = out + (size_t)node * HID + lr;
#pragma unroll
        for (int nt = 0; nt < 8; nt++)
            op[nt * 16] = f2bf(acc[nt][r] + bias[nt * 16 + lr]);
    }
}

// conv GEMM: out[m][n] = Abf[m] @ Wt^T + bias (+ bf16 resid), A bf16 [M][128]
template<int NCHUNK, int NCOLS, bool RESID>
__global__ __launch_bounds__(256)
void k_gemm_mfma(const unsigned short* __restrict__ Abf,
                 const unsigned short* __restrict__ Wt,
                 const float* __restrict__ bias,
                 const unsigned short* __restrict__ resid,
                 float* __restrict__ out, int M)
{
    int tid = threadIdx.x, w = tid >> 6, l = tid & 63, lr = l & 15, lg = l >> 4;
    int base = blockIdx.x * 64 + w * 16;
    int arow = base + lr;
    int asafe = (arow < M) ? arow : M - 1;   // dup rows only affect unstored outputs
    const unsigned short* ap = Abf + (size_t)asafe * HID + lg * 8;
    bf16x8 afrag[4];
#pragma unroll
    for (int kk = 0; kk < 4; kk++) afrag[kk] = *(const bf16x8*)(ap + kk * 32);

    for (int ch = 0; ch < NCHUNK; ch++) {
        f32x4 acc[8];
#pragma unroll
        for (int nt = 0; nt < 8; nt++) acc[nt] = (f32x4){0.f,0.f,0.f,0.f};
        const unsigned short* wp = Wt + ((size_t)(ch * 128) + lr) * HID + lg * 8;
#pragma unroll
        for (int nt = 0; nt < 8; nt++) {
            const unsigned short* wq = wp + nt * 16 * HID;
#pragma unroll
            for (int kk = 0; kk < 4; kk++) {
                bf16x8 bfrag = *(const bf16x8*)(wq + kk * 32);
                acc[nt] = __builtin_amdgcn_mfma_f32_16x16x32_bf16(afrag[kk], bfrag, acc[nt], 0, 0, 0);
            }
        }
#pragma unroll
        for (int r = 0; r < 4; r++) {
            int row = base + lg * 4 + r;
            if (row >= M) continue;
#pragma unroll
            for (int nt = 0; nt < 8; nt++) {
                int col = ch * 128 + nt * 16 + lr;
                if (col < NCOLS) {
                    float v = acc[nt][r] + bias[col];
                    if (RESID) v += bf2f(resid[(size_t)row * HID + col]);
                    out[(size_t)row * NCOLS + col] = v;
                }
            }
        }
    }
}

// ---------------- CSR gather-aggregate (bf16 src -> bf16 out) ----------------

__global__ __launch_bounds__(256)
void k_gather(const unsigned short* __restrict__ src, const int* __restrict__ rowptr,
              const int* __restrict__ packed, const float* __restrict__ rw,
              unsigned short* __restrict__ out, int M)
{
    __shared__ float lut[8];
    int t = threadIdx.x;
    if (t < 8) lut[t] = lrelu(rw[t] * 100.f);
    __syncthreads();
    int wid = t >> 6, lane = t & 63;
    int n = blockIdx.x * 4 + wid;
    if (n >= M) return;
    int e0 = rowptr[n], e1 = rowptr[n + 1];
    float ax = 0.f, ay = 0.f, wsum = 0.f;
    for (int e = e0; e < e1; e++) {
        int p = packed[e];
        float wgt = lut[p >> 20];
        unsigned v = *(const unsigned*)(src + ((size_t)(p & 0xFFFFF)) * HID + lane * 2);
        ax += wgt * __uint_as_float((v & 0xFFFFu) << 16);
        ay += wgt * __uint_as_float(v & 0xFFFF0000u);
        wsum += wgt;
    }
    float inv = (wsum != 0.f) ? 1.f / fabsf(wsum) : 0.f;
    unsigned o = ((unsigned)f2bf(ax * inv)) | (((unsigned)f2bf(ay * inv)) << 16);
    *(unsigned*)(out + (size_t)n * HID + lane * 2) = o;
}

// ---------------- BN + PReLU ----------------

__global__ __launch_bounds__(256)
void k_bn_stats(const float* __restrict__ x, float* __restrict__ sums, int M)
{
    int c = threadIdx.x & 127;
    int rr = threadIdx.x >> 7;
    float s = 0.f, s2 = 0.f;
    for (int r = blockIdx.x * 2 + rr; r < M; r += gridDim.x * 2) {
        float v = x[(size_t)r * HID + c];
        s += v; s2 += v * v;
    }
    atomicAdd(&sums[c], s);
    atomicAdd(&sums[HID + c], s2);
}

__global__
void k_bn_finalize(const float* __restrict__ sums, const float* __restrict__ g,
                   const float* __restrict__ b, float* __restrict__ coef, int M)
{
    int c = threadIdx.x;  // 128 threads
    float inv = 1.f / (float)M;
    float mean = sums[c] * inv;
    float var = sums[HID + c] * inv - mean * mean;
    float sc = g[c] * rsqrtf(var + BN_EPS);
    coef[c] = sc;
    coef[HID + c] = b[c] - mean * sc;
}

__global__ __launch_bounds__(256)
void k_bn_apply(const float* __restrict__ x, const float* __restrict__ coef,
                const float* __restrict__ pa, unsigned short* __restrict__ out, int M)
{
    float a = pa[0];
    int n4 = M * (HID / 4);
    for (int i = blockIdx.x * blockDim.x + threadIdx.x; i < n4;
         i += gridDim.x * blockDim.x) {
        int c4 = (i & 31) * 4;
        float4 v = ((const float4*)x)[i];
        float u0 = v.x * coef[c4+0] + coef[HID+c4+0];
        float u1 = v.y * coef[c4+1] + coef[HID+c4+1];
        float u2 = v.z * coef[c4+2] + coef[HID+c4+2];
        float u3 = v.w * coef[c4+3] + coef[HID+c4+3];
        u0 = u0 >= 0.f ? u0 : a * u0;
        u1 = u1 >= 0.f ? u1 : a * u1;
        u2 = u2 >= 0.f ? u2 : a * u2;
        u3 = u3 >= 0.f ? u3 : a * u3;
        uint2 o;
        o.x = ((unsigned)f2bf(u0)) | (((unsigned)f2bf(u1)) << 16);
        o.y = ((unsigned)f2bf(u2)) | (((unsigned)f2bf(u3)) << 16);
        *(uint2*)(out + (size_t)i * 4) = o;
    }
}

// register-cached log-softmax: 1 read + 1 write per element
__global__ __launch_bounds__(256)
void k_logsoftmax(float* __restrict__ out, int M)
{
    int wid = (int)((blockIdx.x * 256 + threadIdx.x) >> 6);
    int lane = threadIdx.x & 63;
    if (wid >= M) return;
    float* row = out + (size_t)wid * NCLS;
    float rv[6];
    float mx = -1e30f;
#pragma unroll
    for (int k = 0; k < 6; k++) {
        int c = lane + k * 64;
        rv[k] = (c < NCLS) ? row[c] : -1e30f;
        mx = fmaxf(mx, rv[k]);
    }
#pragma unroll
    for (int off = 32; off > 0; off >>= 1) mx = fmaxf(mx, __shfl_xor(mx, off));
    float s = 0.f;
#pragma unroll
    for (int k = 0; k < 6; k++) {
        int c = lane + k * 64;
        if (c < NCLS) s += expf(rv[k] - mx);
    }
#pragma unroll
    for (int off = 32; off > 0; off >>= 1) s += __shfl_xor(s, off);
    float lse = mx + logf(s);
#pragma unroll
    for (int k = 0; k < 6; k++) {
        int c = lane + k * 64;
        if (c < NCLS) row[c] = rv[k] - lse;
    }
}

extern "C" void kernel_launch(void* const* d_in, const int* in_sizes, int n_in,
                              void* d_out, int out_size, void* d_ws, size_t ws_size,
                              hipStream_t stream)
{
    const float* x0      = (const float*)d_in[0];
    const float* x1      = (const float*)d_in[1];
    const int*   ei      = (const int*)d_in[2];
    const int*   et      = (const int*)d_in[3];
    const int*   ntype   = (const int*)d_in[4];
    const int*   lni     = (const int*)d_in[5];
    const float* lin0_w  = (const float*)d_in[6];
    const float* lin0_b  = (const float*)d_in[7];
    const float* lin1_w  = (const float*)d_in[8];
    const float* lin1_b  = (const float*)d_in[9];
    const float* conv0_w = (const float*)d_in[10];
    const float* conv0_b = (const float*)d_in[11];
    const float* conv0_rw= (const float*)d_in[12];
    const float* conv1_w = (const float*)d_in[13];
    const float* conv1_b = (const float*)d_in[14];
    const float* conv1_rw= (const float*)d_in[15];
    const float* bn_g    = (const float*)d_in[16];
    const float* bn_b    = (const float*)d_in[17];
    const float* pa      = (const float*)d_in[18];

    int E = in_sizes[2] / 2;
    int M = in_sizes[4];

    float* ws = (float*)d_ws;
    size_t mh = (size_t)M * HID;
    unsigned short* A  = (unsigned short*)ws;        // h bf16, later xbn bf16
    float*          Bf = ws + mh;                    // region B
    unsigned short* Bu = (unsigned short*)Bf;        // agg bf16
    float*          C  = (float*)d_out;              // conv0 output f32 (dead before final GEMM)
    int*   rowptr  = (int*)(ws + 2 * mh);            // M+1
    int*   packed  = rowptr + (M + 1);               // E (row | et<<20)
    float* bn_sums = (float*)(packed + E);           // 256
    float* bn_coef = bn_sums + 256;                  // 256
    int*   cnt     = (int*)(bn_coef + 256);          // 2
    int*   partials= cnt + 2;                        // 256
    unsigned short* wt_lin0  = (unsigned short*)(partials + 256);
    unsigned short* wt_lin1  = wt_lin0 + 128 * HID;
    unsigned short* wt_conv0 = wt_lin1 + 128 * HID;
    unsigned short* wt_conv1 = wt_conv0 + 128 * HID; // 384*128
    // overlays (dead before their regions' first real write):
    int* cntE  = (int*)A;    // M ints: hist counters, then fill position counters
    int* lists = (int*)Bf;   // 2*M ints: type-partition lists (read before gather0 writes Bu)

    int npart = (M + SCAN_CHUNK - 1) / SCAN_CHUNK;

    hipMemsetAsync(cntE, 0, (size_t)M * sizeof(int), stream);
    hipMemsetAsync(bn_sums, 0, 512 * sizeof(float) + (2 + 256) * sizeof(int), stream);

    // CSR build (shared by both conv layers)
    k_hist<<<(E + 255) / 256, 256, 0, stream>>>(ei, cntE, E);
    k_scan_part<<<npart, 256, 0, stream>>>(cntE, rowptr, partials, M);
    k_scan_base<<<1, 256, 0, stream>>>(partials, rowptr + M, npart);
    k_scan_add<<<npart, 256, 0, stream>>>(rowptr, partials, M);
    hipMemsetAsync(cntE, 0, (size_t)M * sizeof(int), stream);
    k_fill<<<(E + 255) / 256, 256, 0, stream>>>(ei, et, rowptr, cntE, packed, E);

    // node-type partition + weight prep
    k_compact<<<(M + 255) / 256, 256, 0, stream>>>(ntype, cnt, lists, M);
    k_prep_wt<<<64,  256, 0, stream>>>(lin0_w,  wt_lin0,  HID,  128);
    k_prep_wt<<<64,  256, 0, stream>>>(lin1_w,  wt_lin1,  HID,  128);
    k_prep_wt<<<64,  256, 0, stream>>>(conv0_w, wt_conv0, HID,  128);
    k_prep_wt<<<192, 256, 0, stream>>>(conv1_w, wt_conv1, NCLS, 384);

    // grouped input linear (MFMA, fp32->bf16 on load)
    int gblocks = (M + 63) / 64;
    k_gemm_group_mfma<<<gblocks, 256, 0, stream>>>(x0, wt_lin0, lin0_b, lists,     lni, cnt,     A);
    k_gemm_group_mfma<<<gblocks, 256, 0, stream>>>(x1, wt_lin1, lin1_b, lists + M, lni, cnt + 1, A);

    // layer 0: gather-aggregate, conv GEMM + residual
    k_gather<<<(M + 3) / 4, 256, 0, stream>>>(A, rowptr, packed, conv0_rw, Bu, M);
    k_gemm_mfma<1, HID, true><<<gblocks, 256, 0, stream>>>(Bu, wt_conv0, conv0_b, A, C, M);

    // BN + PReLU (writes bf16 xbn over A; h dead after conv0 residual read)
    k_bn_stats<<<512, 256, 0, stream>>>(C, bn_sums, M);
    k_bn_finalize<<<1, 128, 0, stream>>>(bn_sums, bn_g, bn_b, bn_coef, M);
    k_bn_apply<<<2048, 256, 0, stream>>>(C, bn_coef, pa, A, M);

    // layer 1: gather-aggregate, final GEMM into d_out, log-softmax
    k_gather<<<(M + 3) / 4, 256, 0, stream>>>(A, rowptr, packed, conv1_rw, Bu, M);
    k_gemm_mfma<3, NCLS, false><<<gblocks, 256, 0, stream>>>(Bu, wt_conv1, conv1_b, nullptr, (float*)d_out, M);
    k_logsoftmax<<<(M + 3) / 4, 256, 0, stream>>>((float*)d_out, M);
}

// Round 6
// 621.358 us; speedup vs baseline: 3.8152x; 1.0906x over previous
//
#include <hip/hip_runtime.h>
#include <math.h>

#define HID 128
#define NCLS 349
#define BN_EPS 1e-5f
#define SCAN_CHUNK 1024

typedef __attribute__((ext_vector_type(8))) short bf16x8;
typedef __attribute__((ext_vector_type(4))) float f32x4;

__device__ __forceinline__ float lrelu(float v){ return v >= 0.f ? v : 0.01f*v; }

__device__ __forceinline__ unsigned short f2bf(float f){
    unsigned u = __float_as_uint(f);
    u += 0x7FFF + ((u >> 16) & 1);           // RNE
    return (unsigned short)(u >> 16);
}
__device__ __forceinline__ float bf2f(unsigned short s){
    return __uint_as_float(((unsigned)s) << 16);
}

// ---------------- CSR build ----------------

__global__ __launch_bounds__(256)
void k_hist(const int* __restrict__ ei, int* __restrict__ cntE, int E)
{
    int e = blockIdx.x * 256 + threadIdx.x;
    if (e < E) atomicAdd(cntE + ei[E + e], 1);
}

__global__ __launch_bounds__(256)
void k_scan_part(const int* __restrict__ cntE, int* __restrict__ rowptr,
                 int* __restrict__ partials, int M)
{
    __shared__ int sd[256];
    int t = threadIdx.x;
    int base = blockIdx.x * SCAN_CHUNK + t * 4;
    int v[4]; int s = 0;
#pragma unroll
    for (int j = 0; j < 4; j++) { int i = base + j; v[j] = (i < M) ? cntE[i] : 0; s += v[j]; }
    sd[t] = s; __syncthreads();
    for (int off = 1; off < 256; off <<= 1) {
        int x = (t >= off) ? sd[t - off] : 0;
        __syncthreads();
        sd[t] += x;
        __syncthreads();
    }
    int run = sd[t] - s;
    if (t == 255) partials[blockIdx.x] = sd[255];
#pragma unroll
    for (int j = 0; j < 4; j++) { int i = base + j; if (i < M) rowptr[i] = run; run += v[j]; }
}

__global__ __launch_bounds__(256)
void k_scan_base(int* __restrict__ partials, int* __restrict__ rowptr_last, int npart)
{
    __shared__ int sd[256];
    int t = threadIdx.x;
    int v = (t < npart) ? partials[t] : 0;
    sd[t] = v; __syncthreads();
    for (int off = 1; off < 256; off <<= 1) {
        int x = (t >= off) ? sd[t - off] : 0;
        __syncthreads();
        sd[t] += x;
        __syncthreads();
    }
    if (t < npart) partials[t] = sd[t] - v;
    if (t == 255) rowptr_last[0] = sd[255];
}

__global__ __launch_bounds__(256)
void k_scan_add(int* __restrict__ rowptr, const int* __restrict__ partials, int M)
{
    int b = partials[blockIdx.x];
    int base = blockIdx.x * SCAN_CHUNK + threadIdx.x * 4;
#pragma unroll
    for (int j = 0; j < 4; j++) { int i = base + j; if (i < M) rowptr[i] += b; }
}

__global__ __launch_bounds__(256)
void k_fill(const int* __restrict__ ei, const int* __restrict__ et,
            const int* __restrict__ rowptr, int* __restrict__ pos,
            int* __restrict__ packed, int E)
{
    int e = blockIdx.x * 256 + threadIdx.x;
    if (e >= E) return;
    int col = ei[E + e];
    int p = atomicAdd(pos + col, 1);
    packed[rowptr[col] + p] = ei[e] | (et[e] << 20);
}

// ---------------- node-type partition ----------------

__global__ __launch_bounds__(256)
void k_compact(const int* __restrict__ node_type, int* __restrict__ cnt,
               int* __restrict__ lists, int M)
{
    __shared__ int wcnt[4][2];
    __shared__ int bbase[2];
    int tid = threadIdx.x;
    int wid = tid >> 6, lane = tid & 63;
    int i = blockIdx.x * 256 + tid;
    bool valid = i < M;
    int t = valid ? (node_type[i] & 1) : -1;
    unsigned long long m0 = __ballot(t == 0);
    unsigned long long m1 = __ballot(t == 1);
    if (lane == 0) { wcnt[wid][0] = __popcll(m0); wcnt[wid][1] = __popcll(m1); }
    __syncthreads();
    if (tid == 0) {
        int s0 = wcnt[0][0] + wcnt[1][0] + wcnt[2][0] + wcnt[3][0];
        int s1 = wcnt[0][1] + wcnt[1][1] + wcnt[2][1] + wcnt[3][1];
        bbase[0] = atomicAdd(cnt + 0, s0);
        bbase[1] = atomicAdd(cnt + 1, s1);
    }
    __syncthreads();
    int w0 = bbase[0], w1 = bbase[1];
    for (int w = 0; w < wid; w++) { w0 += wcnt[w][0]; w1 += wcnt[w][1]; }
    unsigned long long below = (1ull << lane) - 1ull;
    if (t == 0)      lists[w0 + __popcll(m0 & below)] = i;
    else if (t == 1) lists[M + w1 + __popcll(m1 & below)] = i;
}

// ---------------- weight prep: Wt[col][k] = bf16(W[k][col]), zero-padded cols ----------------

__global__ __launch_bounds__(256)
void k_prep_wt(const float* __restrict__ W, unsigned short* __restrict__ Wt,
               int NCOLS, int NPAD)
{
    int idx = blockIdx.x * 256 + threadIdx.x;
    if (idx >= NPAD * HID) return;
    int col = idx >> 7, k = idx & 127;
    float v = (col < NCOLS) ? W[k * NCOLS + col] : 0.f;
    Wt[idx] = f2bf(v);
}

// ---------------- MFMA GEMMs (16x16x32 bf16, fp32 accum) ----------------
// A/B frag k-map: k = 8*(lane>>4)+j for BOTH operands (same bijection -> correct).
// C/D (m89-verified): col = lane&15, row = (lane>>4)*4 + reg.

// grouped input linear: h[list[g]] = bf16( Xsrc[lni[list[g]]] @ W + b )
__global__ __launch_bounds__(256)
void k_gemm_group_mfma(const float* __restrict__ Xsrc, const unsigned short* __restrict__ Wt,
                       const float* __restrict__ bias, const int* __restrict__ list,
                       const int* __restrict__ lni, const int* __restrict__ cntp,
                       unsigned short* __restrict__ out)
{
    int cnt = *cntp;
    int base = blockIdx.x * 64;
    if (base >= cnt) return;
    int tid = threadIdx.x, w = tid >> 6, l = tid & 63, lr = l & 15, lg = l >> 4;
    int ga = base + w * 16 + lr;
    int node_a = (ga < cnt) ? list[ga] : -1;
    int srow = (node_a >= 0) ? lni[node_a] : 0;
    const float* xp = Xsrc + (size_t)srow * HID + lg * 8;
    bf16x8 afrag[4];
#pragma unroll
    for (int kk = 0; kk < 4; kk++) {
        float4 v0 = *(const float4*)(xp + kk * 32);
        float4 v1 = *(const float4*)(xp + kk * 32 + 4);
        if (node_a < 0) { v0 = make_float4(0,0,0,0); v1 = v0; }
        union { bf16x8 v; short s[8]; } u;
        u.s[0] = (short)f2bf(v0.x); u.s[1] = (short)f2bf(v0.y);
        u.s[2] = (short)f2bf(v0.z); u.s[3] = (short)f2bf(v0.w);
        u.s[4] = (short)f2bf(v1.x); u.s[5] = (short)f2bf(v1.y);
        u.s[6] = (short)f2bf(v1.z); u.s[7] = (short)f2bf(v1.w);
        afrag[kk] = u.v;
    }
    f32x4 acc[8];
#pragma unroll
    for (int nt = 0; nt < 8; nt++) acc[nt] = (f32x4){0.f,0.f,0.f,0.f};
    const unsigned short* wp = Wt + (size_t)lr * HID + lg * 8;
#pragma unroll
    for (int nt = 0; nt < 8; nt++) {
        const unsigned short* wq = wp + nt * 16 * HID;
#pragma unroll
        for (int kk = 0; kk < 4; kk++) {
            bf16x8 bfrag = *(const bf16x8*)(wq + kk * 32);
            acc[nt] = __builtin_amdgcn_mfma_f32_16x16x32_bf16(afrag[kk], bfrag, acc[nt], 0, 0, 0);
        }
    }
#pragma unroll
    for (int r = 0; r < 4; r++) {
        int go = base + w * 16 + lg * 4 + r;
        if (go >= cnt) continue;
        int node = list[go];
        unsigned short* op = out + (size_t)node * HID + lr;
#pragma unroll
        for (int nt = 0; nt < 8; nt++)
            op[nt * 16] = f2bf(acc[nt][r] + bias[nt * 16 + lr]);
    }
}

// conv0 GEMM: out[m][n] = Abf[m] @ Wt^T + bias + bf16 resid  (f32 out)
__global__ __launch_bounds__(256)
void k_gemm_mfma_conv0(const unsigned short* __restrict__ Abf,
                       const unsigned short* __restrict__ Wt,
                       const float* __restrict__ bias,
                       const unsigned short* __restrict__ resid,
                       float* __restrict__ out, int M)
{
    int tid = threadIdx.x, w = tid >> 6, l = tid & 63, lr = l & 15, lg = l >> 4;
    int base = blockIdx.x * 64 + w * 16;
    int arow = base + lr;
    int asafe = (arow < M) ? arow : M - 1;
    const unsigned short* ap = Abf + (size_t)asafe * HID + lg * 8;
    bf16x8 afrag[4];
#pragma unroll
    for (int kk = 0; kk < 4; kk++) afrag[kk] = *(const bf16x8*)(ap + kk * 32);

    f32x4 acc[8];
#pragma unroll
    for (int nt = 0; nt < 8; nt++) acc[nt] = (f32x4){0.f,0.f,0.f,0.f};
    const unsigned short* wp = Wt + (size_t)lr * HID + lg * 8;
#pragma unroll
    for (int nt = 0; nt < 8; nt++) {
        const unsigned short* wq = wp + nt * 16 * HID;
#pragma unroll
        for (int kk = 0; kk < 4; kk++) {
            bf16x8 bfrag = *(const bf16x8*)(wq + kk * 32);
            acc[nt] = __builtin_amdgcn_mfma_f32_16x16x32_bf16(afrag[kk], bfrag, acc[nt], 0, 0, 0);
        }
    }
#pragma unroll
    for (int r = 0; r < 4; r++) {
        int row = base + lg * 4 + r;
        if (row >= M) continue;
#pragma unroll
        for (int nt = 0; nt < 8; nt++) {
            int col = nt * 16 + lr;
            out[(size_t)row * HID + col] =
                acc[nt][r] + bias[col] + bf2f(resid[(size_t)row * HID + col]);
        }
    }
}

// conv1 GEMM fused with log-softmax: d_out[m][n] = logsoftmax(Abf[m] @ Wt^T + b)[n]
// Each wave owns 16 full output rows (all 349 cols in 3x8 f32x4 accs);
// per-row max/sum via in-register reduce + shfl_xor over the 16 lanes sharing lg.
__global__ __launch_bounds__(256)
void k_gemm_softmax(const unsigned short* __restrict__ Abf,
                    const unsigned short* __restrict__ Wt,   // [384][128] bf16
                    const float* __restrict__ bias,          // [349]
                    float* __restrict__ out, int M)
{
    int tid = threadIdx.x, w = tid >> 6, l = tid & 63, lr = l & 15, lg = l >> 4;
    int base = blockIdx.x * 64 + w * 16;
    int arow = base + lr;
    int asafe = (arow < M) ? arow : M - 1;
    const unsigned short* ap = Abf + (size_t)asafe * HID + lg * 8;
    bf16x8 afrag[4];
#pragma unroll
    for (int kk = 0; kk < 4; kk++) afrag[kk] = *(const bf16x8*)(ap + kk * 32);

    f32x4 acc[3][8];
#pragma unroll
    for (int ch = 0; ch < 3; ch++)
#pragma unroll
        for (int nt = 0; nt < 8; nt++) acc[ch][nt] = (f32x4){0.f,0.f,0.f,0.f};

#pragma unroll
    for (int ch = 0; ch < 3; ch++) {
        const unsigned short* wp = Wt + ((size_t)(ch * 128) + lr) * HID + lg * 8;
#pragma unroll
        for (int nt = 0; nt < 8; nt++) {
            const unsigned short* wq = wp + nt * 16 * HID;
#pragma unroll
            for (int kk = 0; kk < 4; kk++) {
                bf16x8 bfrag = *(const bf16x8*)(wq + kk * 32);
                acc[ch][nt] = __builtin_amdgcn_mfma_f32_16x16x32_bf16(afrag[kk], bfrag, acc[ch][nt], 0, 0, 0);
            }
        }
    }

    // bias + mask padded cols; per-row (r) running max
    float mx[4] = {-1e30f, -1e30f, -1e30f, -1e30f};
#pragma unroll
    for (int ch = 0; ch < 3; ch++)
#pragma unroll
        for (int nt = 0; nt < 8; nt++) {
            int col = ch * 128 + nt * 16 + lr;
            float b = (col < NCLS) ? bias[col] : 0.f;
#pragma unroll
            for (int r = 0; r < 4; r++) {
                float v = (col < NCLS) ? (acc[ch][nt][r] + b) : -1e30f;
                acc[ch][nt][r] = v;
                mx[r] = fmaxf(mx[r], v);
            }
        }
#pragma unroll
    for (int off = 1; off < 16; off <<= 1)
#pragma unroll
        for (int r = 0; r < 4; r++) mx[r] = fmaxf(mx[r], __shfl_xor(mx[r], off));

    float sm[4] = {0.f, 0.f, 0.f, 0.f};
#pragma unroll
    for (int ch = 0; ch < 3; ch++)
#pragma unroll
        for (int nt = 0; nt < 8; nt++) {
            int col = ch * 128 + nt * 16 + lr;
            if (col < NCLS) {
#pragma unroll
                for (int r = 0; r < 4; r++) sm[r] += expf(acc[ch][nt][r] - mx[r]);
            }
        }
#pragma unroll
    for (int off = 1; off < 16; off <<= 1)
#pragma unroll
        for (int r = 0; r < 4; r++) sm[r] += __shfl_xor(sm[r], off);

    float lse[4];
#pragma unroll
    for (int r = 0; r < 4; r++) lse[r] = mx[r] + logf(sm[r]);

#pragma unroll
    for (int r = 0; r < 4; r++) {
        int row = base + lg * 4 + r;
        if (row >= M) continue;
        float* op = out + (size_t)row * NCLS;
#pragma unroll
        for (int ch = 0; ch < 3; ch++)
#pragma unroll
            for (int nt = 0; nt < 8; nt++) {
                int col = ch * 128 + nt * 16 + lr;
                if (col < NCLS) op[col] = acc[ch][nt][r] - lse[r];
            }
    }
}

// ---------------- CSR gather-aggregate (bf16 src -> bf16 out) ----------------
// unrolled x2: split accumulators double the load ILP in the latency-bound loop

__global__ __launch_bounds__(256)
void k_gather(const unsigned short* __restrict__ src, const int* __restrict__ rowptr,
              const int* __restrict__ packed, const float* __restrict__ rw,
              unsigned short* __restrict__ out, int M)
{
    __shared__ float lut[8];
    int t = threadIdx.x;
    if (t < 8) lut[t] = lrelu(rw[t] * 100.f);
    __syncthreads();
    int wid = t >> 6, lane = t & 63;
    int n = blockIdx.x * 4 + wid;
    if (n >= M) return;
    int e0 = rowptr[n], e1 = rowptr[n + 1];
    float ax = 0.f, ay = 0.f, aw = 0.f;
    float bx = 0.f, by = 0.f, bw = 0.f;
    int e = e0;
    for (; e + 1 < e1; e += 2) {
        int p0 = packed[e], p1 = packed[e + 1];
        float w0 = lut[p0 >> 20], w1 = lut[p1 >> 20];
        unsigned v0 = *(const unsigned*)(src + ((size_t)(p0 & 0xFFFFF)) * HID + lane * 2);
        unsigned v1 = *(const unsigned*)(src + ((size_t)(p1 & 0xFFFFF)) * HID + lane * 2);
        ax += w0 * __uint_as_float((v0 & 0xFFFFu) << 16);
        ay += w0 * __uint_as_float(v0 & 0xFFFF0000u);
        aw += w0;
        bx += w1 * __uint_as_float((v1 & 0xFFFFu) << 16);
        by += w1 * __uint_as_float(v1 & 0xFFFF0000u);
        bw += w1;
    }
    if (e < e1) {
        int p0 = packed[e];
        float w0 = lut[p0 >> 20];
        unsigned v0 = *(const unsigned*)(src + ((size_t)(p0 & 0xFFFFF)) * HID + lane * 2);
        ax += w0 * __uint_as_float((v0 & 0xFFFFu) << 16);
        ay += w0 * __uint_as_float(v0 & 0xFFFF0000u);
        aw += w0;
    }
    ax += bx; ay += by; aw += bw;
    float inv = (aw != 0.f) ? 1.f / fabsf(aw) : 0.f;
    unsigned o = ((unsigned)f2bf(ax * inv)) | (((unsigned)f2bf(ay * inv)) << 16);
    *(unsigned*)(out + (size_t)n * HID + lane * 2) = o;
}

// ---------------- BN + PReLU ----------------

__global__ __launch_bounds__(256)
void k_bn_stats(const float* __restrict__ x, float* __restrict__ sums, int M)
{
    int c = threadIdx.x & 127;
    int rr = threadIdx.x >> 7;
    float s = 0.f, s2 = 0.f;
    for (int r = blockIdx.x * 2 + rr; r < M; r += gridDim.x * 2) {
        float v = x[(size_t)r * HID + c];
        s += v; s2 += v * v;
    }
    atomicAdd(&sums[c], s);
    atomicAdd(&sums[HID + c], s2);
}

__global__
void k_bn_finalize(const float* __restrict__ sums, const float* __restrict__ g,
                   const float* __restrict__ b, float* __restrict__ coef, int M)
{
    int c = threadIdx.x;  // 128 threads
    float inv = 1.f / (float)M;
    float mean = sums[c] * inv;
    float var = sums[HID + c] * inv - mean * mean;
    float sc = g[c] * rsqrtf(var + BN_EPS);
    coef[c] = sc;
    coef[HID + c] = b[c] - mean * sc;
}

__global__ __launch_bounds__(256)
void k_bn_apply(const float* __restrict__ x, const float* __restrict__ coef,
                const float* __restrict__ pa, unsigned short* __restrict__ out, int M)
{
    float a = pa[0];
    int n4 = M * (HID / 4);
    for (int i = blockIdx.x * blockDim.x + threadIdx.x; i < n4;
         i += gridDim.x * blockDim.x) {
        int c4 = (i & 31) * 4;
        float4 v = ((const float4*)x)[i];
        float u0 = v.x * coef[c4+0] + coef[HID+c4+0];
        float u1 = v.y * coef[c4+1] + coef[HID+c4+1];
        float u2 = v.z * coef[c4+2] + coef[HID+c4+2];
        float u3 = v.w * coef[c4+3] + coef[HID+c4+3];
        u0 = u0 >= 0.f ? u0 : a * u0;
        u1 = u1 >= 0.f ? u1 : a * u1;
        u2 = u2 >= 0.f ? u2 : a * u2;
        u3 = u3 >= 0.f ? u3 : a * u3;
        uint2 o;
        o.x = ((unsigned)f2bf(u0)) | (((unsigned)f2bf(u1)) << 16);
        o.y = ((unsigned)f2bf(u2)) | (((unsigned)f2bf(u3)) << 16);
        *(uint2*)(out + (size_t)i * 4) = o;
    }
}

extern "C" void kernel_launch(void* const* d_in, const int* in_sizes, int n_in,
                              void* d_out, int out_size, void* d_ws, size_t ws_size,
                              hipStream_t stream)
{
    const float* x0      = (const float*)d_in[0];
    const float* x1      = (const float*)d_in[1];
    const int*   ei      = (const int*)d_in[2];
    const int*   et      = (const int*)d_in[3];
    const int*   ntype   = (const int*)d_in[4];
    const int*   lni     = (const int*)d_in[5];
    const float* lin0_w  = (const float*)d_in[6];
    const float* lin0_b  = (const float*)d_in[7];
    const float* lin1_w  = (const float*)d_in[8];
    const float* lin1_b  = (const float*)d_in[9];
    const float* conv0_w = (const float*)d_in[10];
    const float* conv0_b = (const float*)d_in[11];
    const float* conv0_rw= (const float*)d_in[12];
    const float* conv1_w = (const float*)d_in[13];
    const float* conv1_b = (const float*)d_in[14];
    const float* conv1_rw= (const float*)d_in[15];
    const float* bn_g    = (const float*)d_in[16];
    const float* bn_b    = (const float*)d_in[17];
    const float* pa      = (const float*)d_in[18];

    int E = in_sizes[2] / 2;
    int M = in_sizes[4];

    float* ws = (float*)d_ws;
    size_t mh = (size_t)M * HID;
    unsigned short* A  = (unsigned short*)ws;        // h bf16, later xbn bf16
    float*          Bf = ws + mh;                    // region B
    unsigned short* Bu = (unsigned short*)Bf;        // agg bf16
    float*          C  = (float*)d_out;              // conv0 output f32 (dead before final GEMM)
    int*   rowptr  = (int*)(ws + 2 * mh);            // M+1
    int*   packed  = rowptr + (M + 1);               // E (row | et<<20)
    float* bn_sums = (float*)(packed + E);           // 256
    float* bn_coef = bn_sums + 256;                  // 256
    int*   cnt     = (int*)(bn_coef + 256);          // 2
    int*   partials= cnt + 2;                        // 256
    unsigned short* wt_lin0  = (unsigned short*)(partials + 256);
    unsigned short* wt_lin1  = wt_lin0 + 128 * HID;
    unsigned short* wt_conv0 = wt_lin1 + 128 * HID;
    unsigned short* wt_conv1 = wt_conv0 + 128 * HID; // 384*128
    // overlays (dead before their regions' first real write):
    int* cntE  = (int*)A;    // M ints: hist counters, then fill position counters
    int* lists = (int*)Bf;   // 2*M ints: type-partition lists (read before gather0 writes Bu)

    int npart = (M + SCAN_CHUNK - 1) / SCAN_CHUNK;

    hipMemsetAsync(cntE, 0, (size_t)M * sizeof(int), stream);
    hipMemsetAsync(bn_sums, 0, 512 * sizeof(float) + (2 + 256) * sizeof(int), stream);

    // CSR build (shared by both conv layers)
    k_hist<<<(E + 255) / 256, 256, 0, stream>>>(ei, cntE, E);
    k_scan_part<<<npart, 256, 0, stream>>>(cntE, rowptr, partials, M);
    k_scan_base<<<1, 256, 0, stream>>>(partials, rowptr + M, npart);
    k_scan_add<<<npart, 256, 0, stream>>>(rowptr, partials, M);
    hipMemsetAsync(cntE, 0, (size_t)M * sizeof(int), stream);
    k_fill<<<(E + 255) / 256, 256, 0, stream>>>(ei, et, rowptr, cntE, packed, E);

    // node-type partition + weight prep
    k_compact<<<(M + 255) / 256, 256, 0, stream>>>(ntype, cnt, lists, M);
    k_prep_wt<<<64,  256, 0, stream>>>(lin0_w,  wt_lin0,  HID,  128);
    k_prep_wt<<<64,  256, 0, stream>>>(lin1_w,  wt_lin1,  HID,  128);
    k_prep_wt<<<64,  256, 0, stream>>>(conv0_w, wt_conv0, HID,  128);
    k_prep_wt<<<192, 256, 0, stream>>>(conv1_w, wt_conv1, NCLS, 384);

    // grouped input linear (MFMA, fp32->bf16 on load)
    int gblocks = (M + 63) / 64;
    k_gemm_group_mfma<<<gblocks, 256, 0, stream>>>(x0, wt_lin0, lin0_b, lists,     lni, cnt,     A);
    k_gemm_group_mfma<<<gblocks, 256, 0, stream>>>(x1, wt_lin1, lin1_b, lists + M, lni, cnt + 1, A);

    // layer 0: gather-aggregate, conv GEMM + residual
    k_gather<<<(M + 3) / 4, 256, 0, stream>>>(A, rowptr, packed, conv0_rw, Bu, M);
    k_gemm_mfma_conv0<<<gblocks, 256, 0, stream>>>(Bu, wt_conv0, conv0_b, A, C, M);

    // BN + PReLU (writes bf16 xbn over A; h dead after conv0 residual read)
    k_bn_stats<<<512, 256, 0, stream>>>(C, bn_sums, M);
    k_bn_finalize<<<1, 128, 0, stream>>>(bn_sums, bn_g, bn_b, bn_coef, M);
    k_bn_apply<<<2048, 256, 0, stream>>>(C, bn_coef, pa, A, M);

    // layer 1: gather-aggregate, fused final GEMM + log-softmax into d_out
    k_gather<<<(M + 3) / 4, 256, 0, stream>>>(A, rowptr, packed, conv1_rw, Bu, M);
    k_gemm_softmax<<<gblocks, 256, 0, stream>>>(Bu, wt_conv1, conv1_b, (float*)d_out, M);
}

// Round 7
// 518.419 us; speedup vs baseline: 4.5728x; 1.1986x over previous
//
#include <hip/hip_runtime.h>
#include <math.h>

#define HID 128
#define NCLS 349
#define BN_EPS 1e-5f
#define SCAN_CHUNK 1024

typedef __attribute__((ext_vector_type(8))) short bf16x8;
typedef __attribute__((ext_vector_type(4))) float f32x4;

__device__ __forceinline__ float lrelu(float v){ return v >= 0.f ? v : 0.01f*v; }

__device__ __forceinline__ unsigned short f2bf(float f){
    unsigned u = __float_as_uint(f);
    u += 0x7FFF + ((u >> 16) & 1);           // RNE
    return (unsigned short)(u >> 16);
}
__device__ __forceinline__ float bf2f(unsigned short s){
    return __uint_as_float(((unsigned)s) << 16);
}

// LDS weight tile: [col][256B of k], XOR-swizzled so ds_read_b128 spreads
// uniformly over all 8 bank-groups (G4 recipe: byte ^= (col&7)<<4).
#define WSWZ(col, kb) (((col) << 8) + ((kb) ^ (((col) & 7) << 4)))

// stage one 128col x 128k bf16 chunk (32 KB) into LDS; 256 threads, 8x16B each
__device__ __forceinline__ void stage_w(const unsigned short* __restrict__ Wc,
                                        unsigned char* wsm, int tid)
{
#pragma unroll
    for (int i = 0; i < 8; i++) {
        int u = tid + i * 256;                 // 16B unit id, 0..2047
        int col = u >> 4, kb = (u & 15) << 4;
        uint4 v = *(const uint4*)((const unsigned char*)Wc + (size_t)u * 16);
        *(uint4*)(wsm + WSWZ(col, kb)) = v;
    }
}

// ---------------- CSR build ----------------

__global__ __launch_bounds__(256)
void k_hist(const int* __restrict__ ei, int* __restrict__ cntE, int E)
{
    int e = blockIdx.x * 256 + threadIdx.x;
    if (e < E) atomicAdd(cntE + ei[E + e], 1);
}

__global__ __launch_bounds__(256)
void k_scan_part(const int* __restrict__ cntE, int* __restrict__ rowptr,
                 int* __restrict__ partials, int M)
{
    __shared__ int sd[256];
    int t = threadIdx.x;
    int base = blockIdx.x * SCAN_CHUNK + t * 4;
    int v[4]; int s = 0;
#pragma unroll
    for (int j = 0; j < 4; j++) { int i = base + j; v[j] = (i < M) ? cntE[i] : 0; s += v[j]; }
    sd[t] = s; __syncthreads();
    for (int off = 1; off < 256; off <<= 1) {
        int x = (t >= off) ? sd[t - off] : 0;
        __syncthreads();
        sd[t] += x;
        __syncthreads();
    }
    int run = sd[t] - s;
    if (t == 255) partials[blockIdx.x] = sd[255];
#pragma unroll
    for (int j = 0; j < 4; j++) { int i = base + j; if (i < M) rowptr[i] = run; run += v[j]; }
}

__global__ __launch_bounds__(256)
void k_scan_base(int* __restrict__ partials, int* __restrict__ rowptr_last, int npart)
{
    __shared__ int sd[256];
    int t = threadIdx.x;
    int v = (t < npart) ? partials[t] : 0;
    sd[t] = v; __syncthreads();
    for (int off = 1; off < 256; off <<= 1) {
        int x = (t >= off) ? sd[t - off] : 0;
        __syncthreads();
        sd[t] += x;
        __syncthreads();
    }
    if (t < npart) partials[t] = sd[t] - v;
    if (t == 255) rowptr_last[0] = sd[255];
}

__global__ __launch_bounds__(256)
void k_scan_add(int* __restrict__ rowptr, const int* __restrict__ partials, int M)
{
    int b = partials[blockIdx.x];
    int base = blockIdx.x * SCAN_CHUNK + threadIdx.x * 4;
#pragma unroll
    for (int j = 0; j < 4; j++) { int i = base + j; if (i < M) rowptr[i] += b; }
}

__global__ __launch_bounds__(256)
void k_fill(const int* __restrict__ ei, const int* __restrict__ et,
            const int* __restrict__ rowptr, int* __restrict__ pos,
            int* __restrict__ packed, int E)
{
    int e = blockIdx.x * 256 + threadIdx.x;
    if (e >= E) return;
    int col = ei[E + e];
    int p = atomicAdd(pos + col, 1);
    packed[rowptr[col] + p] = ei[e] | (et[e] << 20);
}

// ---------------- node-type partition ----------------

__global__ __launch_bounds__(256)
void k_compact(const int* __restrict__ node_type, int* __restrict__ cnt,
               int* __restrict__ lists, int M)
{
    __shared__ int wcnt[4][2];
    __shared__ int bbase[2];
    int tid = threadIdx.x;
    int wid = tid >> 6, lane = tid & 63;
    int i = blockIdx.x * 256 + tid;
    bool valid = i < M;
    int t = valid ? (node_type[i] & 1) : -1;
    unsigned long long m0 = __ballot(t == 0);
    unsigned long long m1 = __ballot(t == 1);
    if (lane == 0) { wcnt[wid][0] = __popcll(m0); wcnt[wid][1] = __popcll(m1); }
    __syncthreads();
    if (tid == 0) {
        int s0 = wcnt[0][0] + wcnt[1][0] + wcnt[2][0] + wcnt[3][0];
        int s1 = wcnt[0][1] + wcnt[1][1] + wcnt[2][1] + wcnt[3][1];
        bbase[0] = atomicAdd(cnt + 0, s0);
        bbase[1] = atomicAdd(cnt + 1, s1);
    }
    __syncthreads();
    int w0 = bbase[0], w1 = bbase[1];
    for (int w = 0; w < wid; w++) { w0 += wcnt[w][0]; w1 += wcnt[w][1]; }
    unsigned long long below = (1ull << lane) - 1ull;
    if (t == 0)      lists[w0 + __popcll(m0 & below)] = i;
    else if (t == 1) lists[M + w1 + __popcll(m1 & below)] = i;
}

// ---------------- weight prep: Wt[col][k] = bf16(W[k][col]), zero-padded cols ----------------

__global__ __launch_bounds__(256)
void k_prep_wt(const float* __restrict__ W, unsigned short* __restrict__ Wt,
               int NCOLS, int NPAD)
{
    int idx = blockIdx.x * 256 + threadIdx.x;
    if (idx >= NPAD * HID) return;
    int col = idx >> 7, k = idx & 127;
    float v = (col < NCOLS) ? W[k * NCOLS + col] : 0.f;
    Wt[idx] = f2bf(v);
}

// ---------------- MFMA GEMMs (16x16x32 bf16, fp32 accum) ----------------
// A/B frag k-map: k = 8*(lane>>4)+32*kk+j for BOTH operands (same bijection -> correct).
// C/D (m89-verified): col = lane&15, row = (lane>>4)*4 + reg.

// grouped input linear: h[list[g]] = bf16( Xsrc[lni[list[g]]] @ W + b )
__global__ __launch_bounds__(256)
void k_gemm_group_mfma(const float* __restrict__ Xsrc, const unsigned short* __restrict__ Wt,
                       const float* __restrict__ bias, const int* __restrict__ list,
                       const int* __restrict__ lni, const int* __restrict__ cntp,
                       unsigned short* __restrict__ out)
{
    __shared__ uint4 wsm4[2048];                 // 32 KB weight tile
    unsigned char* wsm = (unsigned char*)wsm4;
    int cnt = *cntp;
    int base = blockIdx.x * 64;
    if (base >= cnt) return;
    int tid = threadIdx.x, w = tid >> 6, l = tid & 63, lr = l & 15, lg = l >> 4;

    stage_w(Wt, wsm, tid);

    int ga = base + w * 16 + lr;
    int node_a = (ga < cnt) ? list[ga] : -1;
    int srow = (node_a >= 0) ? lni[node_a] : 0;
    const float* xp = Xsrc + (size_t)srow * HID + lg * 8;
    bf16x8 afrag[4];
#pragma unroll
    for (int kk = 0; kk < 4; kk++) {
        float4 v0 = *(const float4*)(xp + kk * 32);
        float4 v1 = *(const float4*)(xp + kk * 32 + 4);
        if (node_a < 0) { v0 = make_float4(0,0,0,0); v1 = v0; }
        union { bf16x8 v; short s[8]; } u;
        u.s[0] = (short)f2bf(v0.x); u.s[1] = (short)f2bf(v0.y);
        u.s[2] = (short)f2bf(v0.z); u.s[3] = (short)f2bf(v0.w);
        u.s[4] = (short)f2bf(v1.x); u.s[5] = (short)f2bf(v1.y);
        u.s[6] = (short)f2bf(v1.z); u.s[7] = (short)f2bf(v1.w);
        afrag[kk] = u.v;
    }
    __syncthreads();

    f32x4 acc[8];
#pragma unroll
    for (int nt = 0; nt < 8; nt++) acc[nt] = (f32x4){0.f,0.f,0.f,0.f};
#pragma unroll
    for (int nt = 0; nt < 8; nt++) {
        int col = nt * 16 + lr;
#pragma unroll
        for (int kk = 0; kk < 4; kk++) {
            bf16x8 bfrag = *(const bf16x8*)(wsm + WSWZ(col, kk * 64 + lg * 16));
            acc[nt] = __builtin_amdgcn_mfma_f32_16x16x32_bf16(afrag[kk], bfrag, acc[nt], 0, 0, 0);
        }
    }
#pragma unroll
    for (int r = 0; r < 4; r++) {
        int go = base + w * 16 + lg * 4 + r;
        if (go >= cnt) continue;
        int node = list[go];
        unsigned short* op = out + (size_t)node * HID + lr;
#pragma unroll
        for (int nt = 0; nt < 8; nt++)
            op[nt * 16] = f2bf(acc[nt][r] + bias[nt * 16 + lr]);
    }
}

// conv0 GEMM: out[m][n] = Abf[m] @ Wt^T + bias + bf16 resid  (f32 out)
__global__ __launch_bounds__(256)
void k_gemm_mfma_conv0(const unsigned short* __restrict__ Abf,
                       const unsigned short* __restrict__ Wt,
                       const float* __restrict__ bias,
                       const unsigned short* __restrict__ resid,
                       float* __restrict__ out, int M)
{
    __shared__ uint4 wsm4[2048];
    unsigned char* wsm = (unsigned char*)wsm4;
    int tid = threadIdx.x, w = tid >> 6, l = tid & 63, lr = l & 15, lg = l >> 4;

    stage_w(Wt, wsm, tid);

    int base = blockIdx.x * 64 + w * 16;
    int arow = base + lr;
    int asafe = (arow < M) ? arow : M - 1;
    const unsigned short* ap = Abf + (size_t)asafe * HID + lg * 8;
    bf16x8 afrag[4];
#pragma unroll
    for (int kk = 0; kk < 4; kk++) afrag[kk] = *(const bf16x8*)(ap + kk * 32);
    __syncthreads();

    f32x4 acc[8];
#pragma unroll
    for (int nt = 0; nt < 8; nt++) acc[nt] = (f32x4){0.f,0.f,0.f,0.f};
#pragma unroll
    for (int nt = 0; nt < 8; nt++) {
        int col = nt * 16 + lr;
#pragma unroll
        for (int kk = 0; kk < 4; kk++) {
            bf16x8 bfrag = *(const bf16x8*)(wsm + WSWZ(col, kk * 64 + lg * 16));
            acc[nt] = __builtin_amdgcn_mfma_f32_16x16x32_bf16(afrag[kk], bfrag, acc[nt], 0, 0, 0);
        }
    }
#pragma unroll
    for (int r = 0; r < 4; r++) {
        int row = base + lg * 4 + r;
        if (row >= M) continue;
#pragma unroll
        for (int nt = 0; nt < 8; nt++) {
            int col = nt * 16 + lr;
            out[(size_t)row * HID + col] =
                acc[nt][r] + bias[col] + bf2f(resid[(size_t)row * HID + col]);
        }
    }
}

// conv1 GEMM fused with log-softmax: d_out[m][n] = logsoftmax(Abf[m] @ Wt^T + b)[n]
// 3 weight chunks staged through LDS; each wave owns 16 full output rows.
__global__ __launch_bounds__(256)
void k_gemm_softmax(const unsigned short* __restrict__ Abf,
                    const unsigned short* __restrict__ Wt,   // [384][128] bf16
                    const float* __restrict__ bias,          // [349]
                    float* __restrict__ out, int M)
{
    __shared__ uint4 wsm4[2048];
    unsigned char* wsm = (unsigned char*)wsm4;
    int tid = threadIdx.x, w = tid >> 6, l = tid & 63, lr = l & 15, lg = l >> 4;
    int base = blockIdx.x * 64 + w * 16;
    int arow = base + lr;
    int asafe = (arow < M) ? arow : M - 1;
    const unsigned short* ap = Abf + (size_t)asafe * HID + lg * 8;
    bf16x8 afrag[4];
#pragma unroll
    for (int kk = 0; kk < 4; kk++) afrag[kk] = *(const bf16x8*)(ap + kk * 32);

    f32x4 acc[3][8];
#pragma unroll
    for (int ch = 0; ch < 3; ch++)
#pragma unroll
        for (int nt = 0; nt < 8; nt++) acc[ch][nt] = (f32x4){0.f,0.f,0.f,0.f};

#pragma unroll
    for (int ch = 0; ch < 3; ch++) {
        if (ch) __syncthreads();                      // waves done reading prev chunk
        stage_w(Wt + (size_t)ch * 128 * HID, wsm, tid);
        __syncthreads();
#pragma unroll
        for (int nt = 0; nt < 8; nt++) {
            int col = nt * 16 + lr;
#pragma unroll
            for (int kk = 0; kk < 4; kk++) {
                bf16x8 bfrag = *(const bf16x8*)(wsm + WSWZ(col, kk * 64 + lg * 16));
                acc[ch][nt] = __builtin_amdgcn_mfma_f32_16x16x32_bf16(afrag[kk], bfrag, acc[ch][nt], 0, 0, 0);
            }
        }
    }

    // bias + mask padded cols; per-row (r) running max
    float mx[4] = {-1e30f, -1e30f, -1e30f, -1e30f};
#pragma unroll
    for (int ch = 0; ch < 3; ch++)
#pragma unroll
        for (int nt = 0; nt < 8; nt++) {
            int col = ch * 128 + nt * 16 + lr;
            float b = (col < NCLS) ? bias[col] : 0.f;
#pragma unroll
            for (int r = 0; r < 4; r++) {
                float v = (col < NCLS) ? (acc[ch][nt][r] + b) : -1e30f;
                acc[ch][nt][r] = v;
                mx[r] = fmaxf(mx[r], v);
            }
        }
#pragma unroll
    for (int off = 1; off < 16; off <<= 1)
#pragma unroll
        for (int r = 0; r < 4; r++) mx[r] = fmaxf(mx[r], __shfl_xor(mx[r], off));

    float sm[4] = {0.f, 0.f, 0.f, 0.f};
#pragma unroll
    for (int ch = 0; ch < 3; ch++)
#pragma unroll
        for (int nt = 0; nt < 8; nt++) {
            int col = ch * 128 + nt * 16 + lr;
            if (col < NCLS) {
#pragma unroll
                for (int r = 0; r < 4; r++) sm[r] += __expf(acc[ch][nt][r] - mx[r]);
            }
        }
#pragma unroll
    for (int off = 1; off < 16; off <<= 1)
#pragma unroll
        for (int r = 0; r < 4; r++) sm[r] += __shfl_xor(sm[r], off);

    float lse[4];
#pragma unroll
    for (int r = 0; r < 4; r++) lse[r] = mx[r] + __logf(sm[r]);

#pragma unroll
    for (int r = 0; r < 4; r++) {
        int row = base + lg * 4 + r;
        if (row >= M) continue;
        float* op = out + (size_t)row * NCLS;
#pragma unroll
        for (int ch = 0; ch < 3; ch++)
#pragma unroll
            for (int nt = 0; nt < 8; nt++) {
                int col = ch * 128 + nt * 16 + lr;
                if (col < NCLS) op[col] = acc[ch][nt][r] - lse[r];
            }
    }
}

// ---------------- CSR gather-aggregate (bf16 src -> bf16 out) ----------------
// unrolled x4: independent accumulator sets quadruple load ILP

__global__ __launch_bounds__(256)
void k_gather(const unsigned short* __restrict__ src, const int* __restrict__ rowptr,
              const int* __restrict__ packed, const float* __restrict__ rw,
              unsigned short* __restrict__ out, int M)
{
    __shared__ float lut[8];
    int t = threadIdx.x;
    if (t < 8) lut[t] = lrelu(rw[t] * 100.f);
    __syncthreads();
    int wid = t >> 6, lane = t & 63;
    int n = blockIdx.x * 4 + wid;
    if (n >= M) return;
    int e0 = rowptr[n], e1 = rowptr[n + 1];
    float ax = 0.f, ay = 0.f, aw = 0.f;
    float bx = 0.f, by = 0.f, bw = 0.f;
    float cx = 0.f, cy = 0.f, cw = 0.f;
    float dx = 0.f, dy = 0.f, dw = 0.f;
    int e = e0;
    for (; e + 3 < e1; e += 4) {
        int p0 = packed[e], p1 = packed[e + 1], p2 = packed[e + 2], p3 = packed[e + 3];
        float w0 = lut[p0 >> 20], w1 = lut[p1 >> 20], w2 = lut[p2 >> 20], w3 = lut[p3 >> 20];
        unsigned v0 = *(const unsigned*)(src + ((size_t)(p0 & 0xFFFFF)) * HID + lane * 2);
        unsigned v1 = *(const unsigned*)(src + ((size_t)(p1 & 0xFFFFF)) * HID + lane * 2);
        unsigned v2 = *(const unsigned*)(src + ((size_t)(p2 & 0xFFFFF)) * HID + lane * 2);
        unsigned v3 = *(const unsigned*)(src + ((size_t)(p3 & 0xFFFFF)) * HID + lane * 2);
        ax += w0 * __uint_as_float((v0 & 0xFFFFu) << 16);
        ay += w0 * __uint_as_float(v0 & 0xFFFF0000u);
        aw += w0;
        bx += w1 * __uint_as_float((v1 & 0xFFFFu) << 16);
        by += w1 * __uint_as_float(v1 & 0xFFFF0000u);
        bw += w1;
        cx += w2 * __uint_as_float((v2 & 0xFFFFu) << 16);
        cy += w2 * __uint_as_float(v2 & 0xFFFF0000u);
        cw += w2;
        dx += w3 * __uint_as_float((v3 & 0xFFFFu) << 16);
        dy += w3 * __uint_as_float(v3 & 0xFFFF0000u);
        dw += w3;
    }
    for (; e < e1; e++) {
        int p0 = packed[e];
        float w0 = lut[p0 >> 20];
        unsigned v0 = *(const unsigned*)(src + ((size_t)(p0 & 0xFFFFF)) * HID + lane * 2);
        ax += w0 * __uint_as_float((v0 & 0xFFFFu) << 16);
        ay += w0 * __uint_as_float(v0 & 0xFFFF0000u);
        aw += w0;
    }
    ax += bx + cx + dx; ay += by + cy + dy; aw += bw + cw + dw;
    float inv = (aw != 0.f) ? 1.f / fabsf(aw) : 0.f;
    unsigned o = ((unsigned)f2bf(ax * inv)) | (((unsigned)f2bf(ay * inv)) << 16);
    *(unsigned*)(out + (size_t)n * HID + lane * 2) = o;
}

// ---------------- BN + PReLU ----------------

__global__ __launch_bounds__(256)
void k_bn_stats(const float* __restrict__ x, float* __restrict__ sums, int M)
{
    int c = threadIdx.x & 127;
    int rr = threadIdx.x >> 7;
    float s = 0.f, s2 = 0.f;
    for (int r = blockIdx.x * 2 + rr; r < M; r += gridDim.x * 2) {
        float v = x[(size_t)r * HID + c];
        s += v; s2 += v * v;
    }
    atomicAdd(&sums[c], s);
    atomicAdd(&sums[HID + c], s2);
}

__global__
void k_bn_finalize(const float* __restrict__ sums, const float* __restrict__ g,
                   const float* __restrict__ b, float* __restrict__ coef, int M)
{
    int c = threadIdx.x;  // 128 threads
    float inv = 1.f / (float)M;
    float mean = sums[c] * inv;
    float var = sums[HID + c] * inv - mean * mean;
    float sc = g[c] * rsqrtf(var + BN_EPS);
    coef[c] = sc;
    coef[HID + c] = b[c] - mean * sc;
}

__global__ __launch_bounds__(256)
void k_bn_apply(const float* __restrict__ x, const float* __restrict__ coef,
                const float* __restrict__ pa, unsigned short* __restrict__ out, int M)
{
    float a = pa[0];
    int n4 = M * (HID / 4);
    for (int i = blockIdx.x * blockDim.x + threadIdx.x; i < n4;
         i += gridDim.x * blockDim.x) {
        int c4 = (i & 31) * 4;
        float4 v = ((const float4*)x)[i];
        float u0 = v.x * coef[c4+0] + coef[HID+c4+0];
        float u1 = v.y * coef[c4+1] + coef[HID+c4+1];
        float u2 = v.z * coef[c4+2] + coef[HID+c4+2];
        float u3 = v.w * coef[c4+3] + coef[HID+c4+3];
        u0 = u0 >= 0.f ? u0 : a * u0;
        u1 = u1 >= 0.f ? u1 : a * u1;
        u2 = u2 >= 0.f ? u2 : a * u2;
        u3 = u3 >= 0.f ? u3 : a * u3;
        uint2 o;
        o.x = ((unsigned)f2bf(u0)) | (((unsigned)f2bf(u1)) << 16);
        o.y = ((unsigned)f2bf(u2)) | (((unsigned)f2bf(u3)) << 16);
        *(uint2*)(out + (size_t)i * 4) = o;
    }
}

extern "C" void kernel_launch(void* const* d_in, const int* in_sizes, int n_in,
                              void* d_out, int out_size, void* d_ws, size_t ws_size,
                              hipStream_t stream)
{
    const float* x0      = (const float*)d_in[0];
    const float* x1      = (const float*)d_in[1];
    const int*   ei      = (const int*)d_in[2];
    const int*   et      = (const int*)d_in[3];
    const int*   ntype   = (const int*)d_in[4];
    const int*   lni     = (const int*)d_in[5];
    const float* lin0_w  = (const float*)d_in[6];
    const float* lin0_b  = (const float*)d_in[7];
    const float* lin1_w  = (const float*)d_in[8];
    const float* lin1_b  = (const float*)d_in[9];
    const float* conv0_w = (const float*)d_in[10];
    const float* conv0_b = (const float*)d_in[11];
    const float* conv0_rw= (const float*)d_in[12];
    const float* conv1_w = (const float*)d_in[13];
    const float* conv1_b = (const float*)d_in[14];
    const float* conv1_rw= (const float*)d_in[15];
    const float* bn_g    = (const float*)d_in[16];
    const float* bn_b    = (const float*)d_in[17];
    const float* pa      = (const float*)d_in[18];

    int E = in_sizes[2] / 2;
    int M = in_sizes[4];

    float* ws = (float*)d_ws;
    size_t mh = (size_t)M * HID;
    unsigned short* A  = (unsigned short*)ws;        // h bf16, later xbn bf16
    float*          Bf = ws + mh;                    // region B
    unsigned short* Bu = (unsigned short*)Bf;        // agg bf16
    float*          C  = (float*)d_out;              // conv0 output f32 (dead before final GEMM)
    int*   rowptr  = (int*)(ws + 2 * mh);            // M+1
    int*   packed  = rowptr + (M + 1);               // E (row | et<<20)
    float* bn_sums = (float*)(packed + E);           // 256
    float* bn_coef = bn_sums + 256;                  // 256
    int*   cnt     = (int*)(bn_coef + 256);          // 2
    int*   partials= cnt + 2;                        // 256
    unsigned short* wt_lin0  = (unsigned short*)(partials + 256);
    unsigned short* wt_lin1  = wt_lin0 + 128 * HID;
    unsigned short* wt_conv0 = wt_lin1 + 128 * HID;
    unsigned short* wt_conv1 = wt_conv0 + 128 * HID; // 384*128
    // overlays (dead before their regions' first real write):
    int* cntE  = (int*)A;    // M ints: hist counters, then fill position counters
    int* lists = (int*)Bf;   // 2*M ints: type-partition lists (read before gather0 writes Bu)

    int npart = (M + SCAN_CHUNK - 1) / SCAN_CHUNK;

    hipMemsetAsync(cntE, 0, (size_t)M * sizeof(int), stream);
    hipMemsetAsync(bn_sums, 0, 512 * sizeof(float) + (2 + 256) * sizeof(int), stream);

    // CSR build (shared by both conv layers)
    k_hist<<<(E + 255) / 256, 256, 0, stream>>>(ei, cntE, E);
    k_scan_part<<<npart, 256, 0, stream>>>(cntE, rowptr, partials, M);
    k_scan_base<<<1, 256, 0, stream>>>(partials, rowptr + M, npart);
    k_scan_add<<<npart, 256, 0, stream>>>(rowptr, partials, M);
    hipMemsetAsync(cntE, 0, (size_t)M * sizeof(int), stream);
    k_fill<<<(E + 255) / 256, 256, 0, stream>>>(ei, et, rowptr, cntE, packed, E);

    // node-type partition + weight prep
    k_compact<<<(M + 255) / 256, 256, 0, stream>>>(ntype, cnt, lists, M);
    k_prep_wt<<<64,  256, 0, stream>>>(lin0_w,  wt_lin0,  HID,  128);
    k_prep_wt<<<64,  256, 0, stream>>>(lin1_w,  wt_lin1,  HID,  128);
    k_prep_wt<<<64,  256, 0, stream>>>(conv0_w, wt_conv0, HID,  128);
    k_prep_wt<<<192, 256, 0, stream>>>(conv1_w, wt_conv1, NCLS, 384);

    // grouped input linear (MFMA, fp32->bf16 on load)
    int gblocks = (M + 63) / 64;
    k_gemm_group_mfma<<<gblocks, 256, 0, stream>>>(x0, wt_lin0, lin0_b, lists,     lni, cnt,     A);
    k_gemm_group_mfma<<<gblocks, 256, 0, stream>>>(x1, wt_lin1, lin1_b, lists + M, lni, cnt + 1, A);

    // layer 0: gather-aggregate, conv GEMM + residual
    k_gather<<<(M + 3) / 4, 256, 0, stream>>>(A, rowptr, packed, conv0_rw, Bu, M);
    k_gemm_mfma_conv0<<<gblocks, 256, 0, stream>>>(Bu, wt_conv0, conv0_b, A, C, M);

    // BN + PReLU (writes bf16 xbn over A; h dead after conv0 residual read)
    k_bn_stats<<<512, 256, 0, stream>>>(C, bn_sums, M);
    k_bn_finalize<<<1, 128, 0, stream>>>(bn_sums, bn_g, bn_b, bn_coef, M);
    k_bn_apply<<<2048, 256, 0, stream>>>(C, bn_coef, pa, A, M);

    // layer 1: gather-aggregate, fused final GEMM + log-softmax into d_out
    k_gather<<<(M + 3) / 4, 256, 0, stream>>>(A, rowptr, packed, conv1_rw, Bu, M);
    k_gemm_softmax<<<gblocks, 256, 0, stream>>>(Bu, wt_conv1, conv1_b, (float*)d_out, M);
}